// Round 8
// baseline (351.195 us; speedup 1.0000x reference)
//
#include <hip/hip_runtime.h>
#include <math.h>

// Problem constants
// B=2, DIM=256, H=W=32, L=1024, HALF=128, DI=256, DS=16, DTR=8, DEPTH=2, K1=4
#define CH  16      // scan chunk length
#define NCH 64      // chunks per sequence (L / CH)

typedef __attribute__((ext_vector_type(8))) short bf16x8;
typedef __attribute__((ext_vector_type(4))) float f32x4;
typedef __attribute__((ext_vector_type(4))) unsigned int u32x4;

__device__ __forceinline__ float dev_silu(float x){ return x * (1.0f/(1.0f + __expf(-x))); }
__device__ __forceinline__ float dev_softplus(float x){ return fmaxf(x,0.0f) + log1pf(__expf(-fabsf(x))); }
__device__ __forceinline__ unsigned short dev_bf16(float f){
    unsigned int u = __float_as_uint(f);
    return (unsigned short)((u + 0x7fffu + ((u >> 16) & 1u)) >> 16);
}

// ====== prep: proj-weight transpose (blocks 0-63) + fuse-weight bf16 K-reorder (64-639) ======
// Wr[o][kp*256+c] = bf16(fw[o][c][kp]), kp = kh*3+kw
__global__ void __launch_bounds__(256)
k_prep(const float* __restrict__ w1, const float* __restrict__ w2, float* __restrict__ wtc,
       const float* __restrict__ fw, unsigned short* __restrict__ Wr)
{
    if (blockIdx.x < 64){
        int bc = blockIdx.x;           // 8 o-tiles x 8 c-tiles
        int ot = bc & 7, ct = bc >> 3;
        __shared__ float t[32][33];
        int col = threadIdx.x & 31, r8 = threadIdx.x >> 5;
        #pragma unroll
        for (int i = 0; i < 4; ++i){
            int r = i*8 + r8;
            int o = ot*32 + r;
            const float* src = (o < 128) ? (w1 + (size_t)o*256) : (w2 + (size_t)(o-128)*256);
            t[r][col] = src[ct*32 + col];
        }
        __syncthreads();
        #pragma unroll
        for (int i = 0; i < 4; ++i){
            int r = i*8 + r8;
            int c = ct*32 + r, o = ot*32 + col;
            wtc[(size_t)c*256 + o] = t[col][r];
        }
    } else {
        int t0 = ((blockIdx.x - 64)*256 + threadIdx.x)*4;   // 589824 elements total
        unsigned int r[4];
        #pragma unroll
        for (int j = 0; j < 4; ++j){
            int i = t0 + j;
            int o = i / 2304, kk = i - o*2304;
            int kp = kk >> 8, cc = kk & 255;
            r[j] = dev_bf16(fw[(size_t)o*2304 + cc*9 + kp]);
        }
        uint2 pk; pk.x = r[0] | (r[1] << 16); pk.y = r[2] | (r[3] << 16);
        *(uint2*)(Wr + t0) = pk;
    }
}

// ---- proj: block per (b, 4-l tile); coalesced transposed-weight reads ----
__global__ void __launch_bounds__(256)
k_proj(const float* __restrict__ x, const float* __restrict__ wtc,
       const float* __restrict__ b1, const float* __restrict__ b2,
       float* __restrict__ sm, float* __restrict__ sv)
{
    int blk = blockIdx.x;          // b*256 + lt
    int b = blk >> 8, l0 = (blk & 255) * 4;
    int tid = threadIdx.x;
    __shared__ float4 xs[256];
    xs[tid] = *(const float4*)(x + ((size_t)(b*256 + tid))*1024 + l0);
    __syncthreads();
    int o = tid & 127;
    float bias = (tid < 128) ? b1[o] : b2[o];
    float a0 = bias, a1 = bias, a2 = bias, a3 = bias;
    #pragma unroll 4
    for (int c = 0; c < 256; ++c){
        float wv = wtc[(size_t)c*256 + tid];
        float4 xv = xs[c];
        a0 = fmaf(wv, xv.x, a0);
        a1 = fmaf(wv, xv.y, a1);
        a2 = fmaf(wv, xv.z, a2);
        a3 = fmaf(wv, xv.w, a3);
    }
    float* dst = (tid < 128) ? sm : sv;
    size_t base = ((size_t)b*1024 + l0)*128 + o;
    dst[base      ] = a0;
    dst[base + 128] = a1;
    dst[base + 256] = a2;
    dst[base + 384] = a3;
}

// ================= LN(128) + matmul core (v supplied by caller) =================
__device__ __forceinline__ void lnmm_core(int bl0, float4 v,
    const float* __restrict__ lnw, const float* __restrict__ lnb,
    const float* __restrict__ inw, float* __restrict__ u, float* __restrict__ z,
    float (*hn)[132])
{
    int tid = threadIdx.x;
    int row = tid >> 5, lane = tid & 31;
    float a = v.x + v.y + v.z + v.w;
    float q = v.x*v.x + v.y*v.y + v.z*v.z + v.w*v.w;
    #pragma unroll
    for (int o = 16; o; o >>= 1){ a += __shfl_xor(a, o); q += __shfl_xor(q, o); }
    float mean = a * (1.0f/128.0f);
    float rs = rsqrtf(q * (1.0f/128.0f) - mean*mean + 1e-5f);
    float4 w4 = *(const float4*)(lnw + lane*4);
    float4 b4 = *(const float4*)(lnb + lane*4);
    float4 hv;
    hv.x = (v.x-mean)*rs*w4.x + b4.x;
    hv.y = (v.y-mean)*rs*w4.y + b4.y;
    hv.z = (v.z-mean)*rs*w4.z + b4.z;
    hv.w = (v.w-mean)*rs*w4.w + b4.w;
    *(float4*)&hn[row][lane*4] = hv;
    __syncthreads();
    float acc0[8] = {0,0,0,0,0,0,0,0};
    float acc1[8] = {0,0,0,0,0,0,0,0};
    for (int c = 0; c < 128; c += 4){
        float w0[4], w1[4];
        #pragma unroll
        for (int i = 0; i < 4; ++i){
            w0[i] = inw[(size_t)(c+i)*512 + tid];
            w1[i] = inw[(size_t)(c+i)*512 + tid + 256];
        }
        #pragma unroll
        for (int r = 0; r < 8; ++r){
            float4 h4 = *(const float4*)&hn[r][c];
            acc0[r] = fmaf(h4.x, w0[0], acc0[r]);
            acc0[r] = fmaf(h4.y, w0[1], acc0[r]);
            acc0[r] = fmaf(h4.z, w0[2], acc0[r]);
            acc0[r] = fmaf(h4.w, w0[3], acc0[r]);
            acc1[r] = fmaf(h4.x, w1[0], acc1[r]);
            acc1[r] = fmaf(h4.y, w1[1], acc1[r]);
            acc1[r] = fmaf(h4.z, w1[2], acc1[r]);
            acc1[r] = fmaf(h4.w, w1[3], acc1[r]);
        }
    }
    #pragma unroll
    for (int r = 0; r < 8; ++r){
        u[(size_t)(bl0 + r)*256 + tid] = acc0[r];
        z[(size_t)(bl0 + r)*256 + tid] = acc1[r];
    }
}

__global__ void __launch_bounds__(256)
k_lnmm2(const float* __restrict__ sm_, const float* __restrict__ mlnw, const float* __restrict__ mlnb,
        const float* __restrict__ minw, float* __restrict__ um, float* __restrict__ zm,
        const float* __restrict__ sv_, const float* __restrict__ vlnw, const float* __restrict__ vlnb,
        const float* __restrict__ vinw, float* __restrict__ uv, float* __restrict__ zv)
{
    __shared__ float hn[8][132];
    int tid = threadIdx.x;
    int row = tid >> 5, lane = tid & 31;
    if (blockIdx.x < 256){
        int bl0 = blockIdx.x*8;
        float4 v = *(const float4*)(sm_ + (size_t)(bl0 + row)*128 + lane*4);
        lnmm_core(bl0, v, mlnw, mlnb, minw, um, zm, hn);
    } else {
        int bl0 = (blockIdx.x-256)*8;
        float4 v = *(const float4*)(sv_ + (size_t)(bl0 + row)*128 + lane*4);
        lnmm_core(bl0, v, vlnw, vlnb, vinw, uv, zv, hn);
    }
}

// ================= conv: mamba causal K=4 (blocks 0-2047) + vss dw3x3+scatter =================
__global__ void __launch_bounds__(256)
k_conv2(const float* __restrict__ urm, const float* __restrict__ cwm, const float* __restrict__ cbm,
        float* __restrict__ uc,
        const float* __restrict__ urv, const float* __restrict__ cwv, const float* __restrict__ cbv,
        float* __restrict__ us)
{
    int d = threadIdx.x;
    if (blockIdx.x < 2048){
        int bl = blockIdx.x; int b = bl >> 10, l = bl & 1023;
        float acc = cbm[d];
        #pragma unroll
        for (int k = 0; k < 4; ++k){
            int lp = l - 3 + k;
            if (lp >= 0) acc = fmaf(urm[((size_t)(b<<10) + lp)*256 + d], cwm[d*4 + k], acc);
        }
        uc[(size_t)bl*256 + d] = dev_silu(acc);
    } else {
        int bl = blockIdx.x - 2048; int b = bl >> 10, l = bl & 1023;
        int h = l >> 5, w = l & 31;
        float acc = cbv[d];
        #pragma unroll
        for (int kh = 0; kh < 3; ++kh){
            int hh = h + kh - 1; if (hh < 0 || hh > 31) continue;
            #pragma unroll
            for (int kw = 0; kw < 3; ++kw){
                int ww = w + kw - 1; if (ww < 0 || ww > 31) continue;
                acc = fmaf(urv[((size_t)(b<<10) + (hh<<5) + ww)*256 + d], cwv[d*9 + kh*3 + kw], acc);
            }
        }
        float v = dev_silu(acc);
        int l1 = (w<<5) + h;
        size_t base = (size_t)b*4*1024*256;
        us[base + ((size_t)0*1024 + l        )*256 + d] = v;
        us[base + ((size_t)1*1024 + l1       )*256 + d] = v;
        us[base + ((size_t)2*1024 + (1023-l ))*256 + d] = v;
        us[base + ((size_t)3*1024 + (1023-l1))*256 + d] = v;
    }
}

// ===== fused xproj + scanA: block = (bk, chunk of 16 l). dt/du stay in registers. =====
__device__ __forceinline__ void xsa_body(int bk, int ch, int k,
    const float* __restrict__ u, const float* __restrict__ xw,
    const float* __restrict__ dtw, const float* __restrict__ dtb,
    const float* __restrict__ Alog,
    float* __restrict__ dt, float* __restrict__ Bm, float* __restrict__ Cm,
    float* __restrict__ Pb, float* __restrict__ Qb)
{
    int tid = threadIdx.x;
    __shared__ float ursh[16][256];
    __shared__ float xwsh[64][40];
    __shared__ float dbc[16][44];
    size_t idx0 = (size_t)bk*1024 + ch*CH;
    #pragma unroll
    for (int p = 0; p < 16; ++p)
        ursh[p][tid] = u[(idx0 + p)*256 + tid];
    const float* xwk = xw + (size_t)k*256*40;
    int pp[3], rr[3];
    #pragma unroll
    for (int rnd = 0; rnd < 3; ++rnd){
        int t = rnd*256 + tid;
        pp[rnd] = t/40; rr[rnd] = t - pp[rnd]*40;
    }
    float accd[3] = {0.f, 0.f, 0.f};
    for (int ct = 0; ct < 4; ++ct){
        __syncthreads();
        for (int i = tid; i < 64*40; i += 256)
            xwsh[i/40][i%40] = xwk[(size_t)(ct*64 + i/40)*40 + (i%40)];
        __syncthreads();
        #pragma unroll
        for (int rnd = 0; rnd < 3; ++rnd){
            int t = rnd*256 + tid;
            if (t < 640){
                int p = pp[rnd], r = rr[rnd];
                float a = accd[rnd];
                #pragma unroll 8
                for (int cc = 0; cc < 64; ++cc)
                    a = fmaf(ursh[p][ct*64 + cc], xwsh[cc][r], a);
                accd[rnd] = a;
            }
        }
    }
    __syncthreads();
    #pragma unroll
    for (int rnd = 0; rnd < 3; ++rnd){
        int t = rnd*256 + tid;
        if (t < 640) dbc[pp[rnd]][rr[rnd]] = accd[rnd];
    }
    __syncthreads();
    // dt + du (registers), d = tid
    const float* dtwk = dtw + (size_t)k*8*256;
    float bias = dtb[k*256 + tid];
    float wv[8];
    #pragma unroll
    for (int r = 0; r < 8; ++r) wv[r] = dtwk[r*256 + tid];
    float dtv[16], duv[16];
    #pragma unroll
    for (int p = 0; p < 16; ++p){
        float a = bias;
        #pragma unroll
        for (int r = 0; r < 8; ++r) a = fmaf(dbc[p][r], wv[r], a);
        a = dev_softplus(a);
        dtv[p] = a;
        dt[(idx0 + p)*256 + tid] = a;
        duv[p] = a * ursh[p][tid];
    }
    {   // B/C for scanB: 256 threads = 16 p x 16 s
        int p = tid >> 4, s = tid & 15;
        Bm[(idx0 + p)*16 + s] = dbc[p][8 + s];
        Cm[(idx0 + p)*16 + s] = dbc[p][24 + s];
    }
    float A[16];
    const float4* Ap = (const float4*)(Alog + ((size_t)k*256 + tid)*16);
    #pragma unroll
    for (int q = 0; q < 4; ++q){
        float4 v = Ap[q];
        A[q*4+0] = -__expf(v.x); A[q*4+1] = -__expf(v.y);
        A[q*4+2] = -__expf(v.z); A[q*4+3] = -__expf(v.w);
    }
    float Q[16];
    #pragma unroll
    for (int s = 0; s < 16; ++s) Q[s] = 0.f;
    float S = 0.f;
    #pragma unroll
    for (int j = 0; j < 16; ++j){
        S += dtv[j];
        #pragma unroll
        for (int s = 0; s < 16; ++s){
            float av = __expf(dtv[j]*A[s]);
            Q[s] = fmaf(av, Q[s], duv[j]*dbc[j][8 + s]);
        }
    }
    size_t oidx = ((size_t)(bk*NCH + ch)*256 + tid)*16;
    float4* Pp = (float4*)(Pb + oidx);
    float4* Qp = (float4*)(Qb + oidx);
    #pragma unroll
    for (int q = 0; q < 4; ++q){
        float4 pv, qv;
        pv.x = __expf(S*A[q*4+0]); pv.y = __expf(S*A[q*4+1]);
        pv.z = __expf(S*A[q*4+2]); pv.w = __expf(S*A[q*4+3]);
        qv.x = Q[q*4+0]; qv.y = Q[q*4+1]; qv.z = Q[q*4+2]; qv.w = Q[q*4+3];
        Pp[q] = pv; Qp[q] = qv;
    }
}

__global__ void __launch_bounds__(256)
k_xsa2(const float* __restrict__ um, const float* __restrict__ mxw, const float* __restrict__ mdtw,
       const float* __restrict__ mdtb, const float* __restrict__ mAlog,
       float* __restrict__ dtm, float* __restrict__ Bmm, float* __restrict__ Cmm,
       float* __restrict__ Pbm, float* __restrict__ Qbm,
       const float* __restrict__ uv, const float* __restrict__ vxw, const float* __restrict__ vdtw,
       const float* __restrict__ vdtb, const float* __restrict__ vAlog,
       float* __restrict__ dtv_, float* __restrict__ Bmv, float* __restrict__ Cmv,
       float* __restrict__ Pbv, float* __restrict__ Qbv)
{
    if (blockIdx.x < 128){
        int blk = blockIdx.x;
        xsa_body(blk >> 6, blk & 63, 0, um, mxw, mdtw, mdtb, mAlog, dtm, Bmm, Cmm, Pbm, Qbm);
    } else {
        int blk = blockIdx.x - 128;
        int bk = blk >> 6;
        xsa_body(bk, blk & 63, bk & 3, uv, vxw, vdtw, vdtb, vAlog, dtv_, Bmv, Cmv, Pbv, Qbv);
    }
}

// ================= scan pass P =================
__device__ __forceinline__ void scanP_body(int bk, int dg, float* __restrict__ Pb,
                                           const float* __restrict__ Qb)
{
    int tid = threadIdx.x;
    size_t idx0 = (size_t)bk*NCH*4096 + dg*256 + tid;
    float Pv[NCH], Qv[NCH];
    #pragma unroll
    for (int c = 0; c < NCH; ++c){
        Pv[c] = Pb[idx0 + (size_t)c*4096];
        Qv[c] = Qb[idx0 + (size_t)c*4096];
    }
    float h = 0.f;
    #pragma unroll
    for (int c = 0; c < NCH; ++c){
        Pb[idx0 + (size_t)c*4096] = h;
        h = fmaf(Pv[c], h, Qv[c]);
    }
}

__global__ void __launch_bounds__(256)
k_scanP2(float* __restrict__ Pbm, const float* __restrict__ Qbm,
         float* __restrict__ Pbv, const float* __restrict__ Qbv)
{
    if (blockIdx.x < 32) scanP_body(blockIdx.x >> 4, blockIdx.x & 15, Pbm, Qbm);
    else { int blk = blockIdx.x - 32; scanP_body(blk >> 4, blk & 15, Pbv, Qbv); }
}

// ================= scan pass B =================
__device__ __forceinline__ void scanB_body(int bk, int c, int k, const float* __restrict__ dt,
    const float* __restrict__ u, const float* __restrict__ Bm, const float* __restrict__ Cm,
    const float* __restrict__ Alog, const float* __restrict__ Hb, float* __restrict__ y)
{
    int d = threadIdx.x;
    __shared__ float Bsh[CH][16], Csh[CH][16];
    {
        int j = threadIdx.x >> 4, s = threadIdx.x & 15;
        size_t bi = ((size_t)bk*1024 + c*CH + j)*16 + s;
        Bsh[j][s] = Bm[bi];
        Csh[j][s] = Cm[bi];
    }
    float dtv[CH], duv[CH];
    size_t base = ((size_t)bk*1024 + c*CH)*256 + d;
    #pragma unroll
    for (int j = 0; j < CH; ++j){
        float a = dt[base + (size_t)j*256];
        float b = u [base + (size_t)j*256];
        dtv[j] = a; duv[j] = a*b;
    }
    float A[16];
    const float4* Ap = (const float4*)(Alog + ((size_t)k*256 + d)*16);
    #pragma unroll
    for (int q = 0; q < 4; ++q){
        float4 v = Ap[q];
        A[q*4+0] = -__expf(v.x); A[q*4+1] = -__expf(v.y);
        A[q*4+2] = -__expf(v.z); A[q*4+3] = -__expf(v.w);
    }
    float h[16];
    const float4* Hp = (const float4*)(Hb + ((size_t)(bk*NCH + c)*256 + d)*16);
    #pragma unroll
    for (int q = 0; q < 4; ++q){
        float4 v = Hp[q];
        h[q*4+0] = v.x; h[q*4+1] = v.y; h[q*4+2] = v.z; h[q*4+3] = v.w;
    }
    __syncthreads();
    float* yp = y + base;
    #pragma unroll
    for (int j = 0; j < CH; ++j){
        float py = 0.f;
        #pragma unroll
        for (int s = 0; s < 16; ++s){
            float av = __expf(dtv[j]*A[s]);
            h[s] = fmaf(av, h[s], duv[j]*Bsh[j][s]);
            py = fmaf(h[s], Csh[j][s], py);
        }
        yp[(size_t)j*256] = py;
    }
}

__global__ void __launch_bounds__(256)
k_scanB2(const float* __restrict__ dtm, const float* __restrict__ um, const float* __restrict__ Bmm,
         const float* __restrict__ Cmm, const float* __restrict__ mAlog,
         const float* __restrict__ Hbm, float* __restrict__ ym,
         const float* __restrict__ dtv, const float* __restrict__ uv, const float* __restrict__ Bmv,
         const float* __restrict__ Cmv, const float* __restrict__ vAlog,
         const float* __restrict__ Hbv, float* __restrict__ yv)
{
    if (blockIdx.x < 128){
        int blk = blockIdx.x;
        scanB_body(blk >> 6, blk & (NCH-1), 0, dtm, um, Bmm, Cmm, mAlog, Hbm, ym);
    } else {
        int blk = blockIdx.x - 128;
        int bk = blk >> 6;
        scanB_body(bk, blk & (NCH-1), bk & 3, dtv, uv, Bmv, Cmv, vAlog, Hbv, yv);
    }
}

// ================= epilogues (write updated rows to LDS for optional fused LN) ========
__device__ __forceinline__ void mout_body(int bl0, const float* __restrict__ y,
    const float* __restrict__ uc, const float* __restrict__ z, const float* __restrict__ Dp,
    const float* __restrict__ ow, float* __restrict__ sm, float* __restrict__ srowp)
{
    int tid = threadIdx.x;
    int row = tid >> 5, c0 = (tid & 31) * 8;
    __shared__ float gld[8][264];
    size_t base = (size_t)(bl0 + row)*256 + c0;
    #pragma unroll
    for (int i = 0; i < 8; i += 4){
        float4 yv = *(const float4*)(y + base + i);
        float4 uv = *(const float4*)(uc + base + i);
        float4 zv = *(const float4*)(z + base + i);
        float4 dv = *(const float4*)(Dp + c0 + i);
        gld[row][c0+i+0] = (yv.x + uv.x*dv.x) * dev_silu(zv.x);
        gld[row][c0+i+1] = (yv.y + uv.y*dv.y) * dev_silu(zv.y);
        gld[row][c0+i+2] = (yv.z + uv.z*dv.z) * dev_silu(zv.z);
        gld[row][c0+i+3] = (yv.w + uv.w*dv.w) * dev_silu(zv.w);
    }
    __syncthreads();
    int o = tid & 127, rg = tid >> 7;
    float acc[4] = {0,0,0,0};
    for (int c = 0; c < 256; c += 4){
        float w[4];
        #pragma unroll
        for (int i = 0; i < 4; ++i) w[i] = ow[(size_t)(c+i)*128 + o];
        #pragma unroll
        for (int r = 0; r < 4; ++r){
            float4 h4 = *(const float4*)&gld[rg*4 + r][c];
            acc[r] = fmaf(h4.x, w[0], acc[r]);
            acc[r] = fmaf(h4.y, w[1], acc[r]);
            acc[r] = fmaf(h4.z, w[2], acc[r]);
            acc[r] = fmaf(h4.w, w[3], acc[r]);
        }
    }
    #pragma unroll
    for (int r = 0; r < 4; ++r){
        size_t gi = (size_t)(bl0 + rg*4 + r)*128 + o;
        float nv = sm[gi] + acc[r];
        sm[gi] = nv;
        srowp[(rg*4 + r)*128 + o] = nv;
    }
}

__device__ __forceinline__ void vcomb_body(int blk, const float* __restrict__ y,
    const float* __restrict__ us, const float* __restrict__ z, const float* __restrict__ Dp,
    const float* __restrict__ onw, const float* __restrict__ onb, const float* __restrict__ ow,
    float* __restrict__ sv, float* __restrict__ srowp)
{
    int b = blk >> 7;
    int l0 = (blk & 127) * 8;
    int tid = threadIdx.x;
    int row = tid >> 5, c0 = (tid & 31) * 8;
    int l = l0 + row;
    int h = l >> 5, w = l & 31;
    int l1 = (w<<5) + h, l2 = 1023 - l, l3 = 1023 - l1;
    size_t base = (size_t)b*4*1024*256;
    size_t i0 = base + ((size_t)0*1024 + l )*256 + c0;
    size_t i1 = base + ((size_t)1*1024 + l1)*256 + c0;
    size_t i2 = base + ((size_t)2*1024 + l2)*256 + c0;
    size_t i3 = base + ((size_t)3*1024 + l3)*256 + c0;
    float t[8];
    #pragma unroll
    for (int i = 0; i < 8; i += 4){
        float4 yv = *(const float4*)(y + i0 + i);
        float4 uv = *(const float4*)(us + i0 + i);
        float4 dv = *(const float4*)(Dp + 0*256 + c0 + i);
        t[i+0] = yv.x + uv.x*dv.x; t[i+1] = yv.y + uv.y*dv.y;
        t[i+2] = yv.z + uv.z*dv.z; t[i+3] = yv.w + uv.w*dv.w;
    }
    #pragma unroll
    for (int i = 0; i < 8; i += 4){
        float4 yv = *(const float4*)(y + i1 + i);
        float4 uv = *(const float4*)(us + i1 + i);
        float4 dv = *(const float4*)(Dp + 1*256 + c0 + i);
        t[i+0] += yv.x + uv.x*dv.x; t[i+1] += yv.y + uv.y*dv.y;
        t[i+2] += yv.z + uv.z*dv.z; t[i+3] += yv.w + uv.w*dv.w;
    }
    #pragma unroll
    for (int i = 0; i < 8; i += 4){
        float4 yv = *(const float4*)(y + i2 + i);
        float4 uv = *(const float4*)(us + i2 + i);
        float4 dv = *(const float4*)(Dp + 2*256 + c0 + i);
        t[i+0] += yv.x + uv.x*dv.x; t[i+1] += yv.y + uv.y*dv.y;
        t[i+2] += yv.z + uv.z*dv.z; t[i+3] += yv.w + uv.w*dv.w;
    }
    #pragma unroll
    for (int i = 0; i < 8; i += 4){
        float4 yv = *(const float4*)(y + i3 + i);
        float4 uv = *(const float4*)(us + i3 + i);
        float4 dv = *(const float4*)(Dp + 3*256 + c0 + i);
        t[i+0] += yv.x + uv.x*dv.x; t[i+1] += yv.y + uv.y*dv.y;
        t[i+2] += yv.z + uv.z*dv.z; t[i+3] += yv.w + uv.w*dv.w;
    }
    float a = 0.f, q = 0.f;
    #pragma unroll
    for (int i = 0; i < 8; ++i){ a += t[i]; q += t[i]*t[i]; }
    #pragma unroll
    for (int o = 16; o; o >>= 1){ a += __shfl_xor(a, o); q += __shfl_xor(q, o); }
    float mean = a * (1.0f/256.0f);
    float rs = rsqrtf(q * (1.0f/256.0f) - mean*mean + 1e-5f);
    __shared__ float gld[8][264];
    size_t zbase = (size_t)(b*1024 + l)*256 + c0;
    #pragma unroll
    for (int i = 0; i < 8; i += 4){
        float4 wv = *(const float4*)(onw + c0 + i);
        float4 bv = *(const float4*)(onb + c0 + i);
        float4 zv = *(const float4*)(z + zbase + i);
        gld[row][c0+i+0] = ((t[i+0]-mean)*rs*wv.x + bv.x) * dev_silu(zv.x);
        gld[row][c0+i+1] = ((t[i+1]-mean)*rs*wv.y + bv.y) * dev_silu(zv.y);
        gld[row][c0+i+2] = ((t[i+2]-mean)*rs*wv.z + bv.z) * dev_silu(zv.z);
        gld[row][c0+i+3] = ((t[i+3]-mean)*rs*wv.w + bv.w) * dev_silu(zv.w);
    }
    __syncthreads();
    int o = tid & 127, rg = tid >> 7;
    float acc[4] = {0,0,0,0};
    for (int c = 0; c < 256; c += 4){
        float wv[4];
        #pragma unroll
        for (int i = 0; i < 4; ++i) wv[i] = ow[(size_t)(c+i)*128 + o];
        #pragma unroll
        for (int r = 0; r < 4; ++r){
            float4 h4 = *(const float4*)&gld[rg*4 + r][c];
            acc[r] = fmaf(h4.x, wv[0], acc[r]);
            acc[r] = fmaf(h4.y, wv[1], acc[r]);
            acc[r] = fmaf(h4.z, wv[2], acc[r]);
            acc[r] = fmaf(h4.w, wv[3], acc[r]);
        }
    }
    #pragma unroll
    for (int r = 0; r < 4; ++r){
        size_t gi = (size_t)(b*1024 + l0 + rg*4 + r)*128 + o;
        float nv = sv[gi] + acc[r];
        sv[gi] = nv;
        srowp[(rg*4 + r)*128 + o] = nv;
    }
}

// final-layer epilogue (no fused LN)
__global__ void __launch_bounds__(256)
k_epi2(const float* __restrict__ ym, const float* __restrict__ uc, const float* __restrict__ zm,
       const float* __restrict__ mD, const float* __restrict__ mow, float* __restrict__ sm,
       const float* __restrict__ yv, const float* __restrict__ us, const float* __restrict__ zv,
       const float* __restrict__ vD, const float* __restrict__ onw, const float* __restrict__ onb,
       const float* __restrict__ vow, float* __restrict__ sv)
{
    __shared__ float srow[8][128];
    if (blockIdx.x < 256) mout_body(blockIdx.x*8, ym, uc, zm, mD, mow, sm, &srow[0][0]);
    else                  vcomb_body(blockIdx.x-256, yv, us, zv, vD, onw, onb, vow, sv, &srow[0][0]);
}

// epilogue + next-layer LN/in-proj fused
__global__ void __launch_bounds__(256)
k_epln2(const float* __restrict__ ym, const float* __restrict__ uc, const float* __restrict__ zm,
        const float* __restrict__ mD, const float* __restrict__ mow, float* __restrict__ sm,
        const float* __restrict__ yv, const float* __restrict__ us, const float* __restrict__ zv,
        const float* __restrict__ vD, const float* __restrict__ onw, const float* __restrict__ onb,
        const float* __restrict__ vow, float* __restrict__ sv,
        const float* __restrict__ mlnw, const float* __restrict__ mlnb, const float* __restrict__ minw,
        float* __restrict__ um_o, float* __restrict__ zm_o,
        const float* __restrict__ vlnw, const float* __restrict__ vlnb, const float* __restrict__ vinw,
        float* __restrict__ uv_o, float* __restrict__ zv_o)
{
    __shared__ float srow[8][128];
    __shared__ float hn[8][132];
    int tid = threadIdx.x;
    int row = tid >> 5, lane = tid & 31;
    if (blockIdx.x < 256){
        int bl0 = blockIdx.x*8;
        mout_body(bl0, ym, uc, zm, mD, mow, sm, &srow[0][0]);
        __syncthreads();
        float4 v = *(const float4*)&srow[row][lane*4];
        lnmm_core(bl0, v, mlnw, mlnb, minw, um_o, zm_o, hn);
    } else {
        int blk = blockIdx.x - 256;
        int bl0 = (blk >> 7)*1024 + (blk & 127)*8;
        vcomb_body(blk, yv, us, zv, vD, onw, onb, vow, sv, &srow[0][0]);
        __syncthreads();
        float4 v = *(const float4*)&srow[row][lane*4];
        lnmm_core(bl0, v, vlnw, vlnb, vinw, uv_o, zv_o, hn);
    }
}

// ---- bf16 MFMA GEMM with inline im2col (K reordered: kp major, c minor) ----
// out[o][n] = sum_k Wr[o][k] * B[n][k];  B[n][kp*256+c] = concat(sm,sv)[b][l'(kp)][c] (0-pad)
__global__ void __launch_bounds__(256)
k_fgemm(const unsigned short* __restrict__ Wr, const float* __restrict__ sm,
        const float* __restrict__ sv, const float* __restrict__ fb,
        const float* __restrict__ bg, const float* __restrict__ bb,
        const float* __restrict__ bm, const float* __restrict__ bv, float* __restrict__ out)
{
    int o0 = (blockIdx.x & 3) * 64;
    int n0 = (blockIdx.x >> 2) * 64;
    int tid = threadIdx.x, lane = tid & 63, wid = tid >> 6;
    int wm = (wid >> 1) * 32, wn = (wid & 1) * 32;
    __shared__ unsigned short sA[64*40];
    __shared__ unsigned short sB[64*40];
    f32x4 acc[2][2] = {};
    int srow = tid >> 2, scol = (tid & 3) * 8;
    const u32x4* gA = (const u32x4*)(Wr + (size_t)(o0 + srow)*2304 + scol);
    u32x4* wA = (u32x4*)(sA + srow*40 + scol);
    u32x4* wB = (u32x4*)(sB + srow*40 + scol);
    // B gather geometry for this thread's row
    int n = n0 + srow; int b = n >> 10, p = n & 1023, h = p >> 5, w = p & 31;
    int fr = lane & 15, fk = (lane >> 4) * 8;
    const unsigned short* rA0 = sA + (wm + fr)*40 + fk;
    const unsigned short* rA1 = sA + (wm + 16 + fr)*40 + fk;
    const unsigned short* rB0 = sB + (wn + fr)*40 + fk;
    const unsigned short* rB1 = sB + (wn + 16 + fr)*40 + fk;
    for (int kt = 0; kt < 72; ++kt){
        u32x4 va = gA[kt*4];
        int kp = kt >> 3, c0 = (kt & 7) * 32;
        int kh = kp / 3, kw = kp - kh*3;
        int hh = h + kh - 1, ww = w + kw - 1;
        int cg = c0 + scol;
        float4 v0 = make_float4(0.f,0.f,0.f,0.f), v1 = v0;
        if ((unsigned)hh < 32u && (unsigned)ww < 32u){
            const float* sp = ((cg < 128) ? sm : sv)
                            + ((size_t)(b*1024 + (hh<<5) + ww))*128 + (cg & 127);
            v0 = *(const float4*)sp;
            v1 = *(const float4*)(sp + 4);
        }
        u32x4 vb;
        vb.x = dev_bf16(v0.x) | ((unsigned)dev_bf16(v0.y) << 16);
        vb.y = dev_bf16(v0.z) | ((unsigned)dev_bf16(v0.w) << 16);
        vb.z = dev_bf16(v1.x) | ((unsigned)dev_bf16(v1.y) << 16);
        vb.w = dev_bf16(v1.z) | ((unsigned)dev_bf16(v1.w) << 16);
        __syncthreads();
        *wA = va; *wB = vb;
        __syncthreads();
        bf16x8 a0 = *(const bf16x8*)rA0;
        bf16x8 a1 = *(const bf16x8*)rA1;
        bf16x8 b0 = *(const bf16x8*)rB0;
        bf16x8 b1 = *(const bf16x8*)rB1;
        acc[0][0] = __builtin_amdgcn_mfma_f32_16x16x32_bf16(a0, b0, acc[0][0], 0, 0, 0);
        acc[0][1] = __builtin_amdgcn_mfma_f32_16x16x32_bf16(a0, b1, acc[0][1], 0, 0, 0);
        acc[1][0] = __builtin_amdgcn_mfma_f32_16x16x32_bf16(a1, b0, acc[1][0], 0, 0, 0);
        acc[1][1] = __builtin_amdgcn_mfma_f32_16x16x32_bf16(a1, b1, acc[1][1], 0, 0, 0);
    }
    #pragma unroll
    for (int i = 0; i < 2; ++i){
        int ob = o0 + wm + i*16 + (lane >> 4) * 4;
        #pragma unroll
        for (int j = 0; j < 2; ++j){
            int nn = n0 + wn + j*16 + (lane & 15);
            int bb_ = nn >> 10, pp = nn & 1023;
            #pragma unroll
            for (int q = 0; q < 4; ++q){
                int o = ob + q;
                float v = acc[i][j][q] + fb[o];
                v = (v - bm[o]) * rsqrtf(bv[o] + 1e-5f) * bg[o] + bb[o];
                out[((size_t)(bb_*256 + o))*1024 + pp] = fmaxf(v, 0.f);
            }
        }
    }
}

extern "C" void kernel_launch(void* const* d_in, const int* in_sizes, int n_in,
                              void* d_out, int out_size, void* d_ws, size_t ws_size,
                              hipStream_t stream)
{
    const float* x         = (const float*)d_in[0];
    const float* proj1_w   = (const float*)d_in[1];
    const float* proj1_b   = (const float*)d_in[2];
    const float* proj2_w   = (const float*)d_in[3];
    const float* proj2_b   = (const float*)d_in[4];
    const float* m_ln_w    = (const float*)d_in[5];
    const float* m_ln_b    = (const float*)d_in[6];
    const float* m_in_w    = (const float*)d_in[7];
    const float* m_conv_w  = (const float*)d_in[8];
    const float* m_conv_b  = (const float*)d_in[9];
    const float* m_xproj_w = (const float*)d_in[10];
    const float* m_dt_w    = (const float*)d_in[11];
    const float* m_dt_b    = (const float*)d_in[12];
    const float* m_Alog    = (const float*)d_in[13];
    const float* m_D       = (const float*)d_in[14];
    const float* m_out_w   = (const float*)d_in[15];
    const float* v_ln_w    = (const float*)d_in[16];
    const float* v_ln_b    = (const float*)d_in[17];
    const float* v_in_w    = (const float*)d_in[18];
    const float* v_conv_w  = (const float*)d_in[19];
    const float* v_conv_b  = (const float*)d_in[20];
    const float* v_xproj_w = (const float*)d_in[21];
    const float* v_dt_w    = (const float*)d_in[22];
    const float* v_dt_b    = (const float*)d_in[23];
    const float* v_Alog    = (const float*)d_in[24];
    const float* v_D       = (const float*)d_in[25];
    const float* v_onorm_w = (const float*)d_in[26];
    const float* v_onorm_b = (const float*)d_in[27];
    const float* v_out_w   = (const float*)d_in[28];
    const float* fuse_w    = (const float*)d_in[29];
    const float* fuse_b    = (const float*)d_in[30];
    const float* bn_g      = (const float*)d_in[31];
    const float* bn_b      = (const float*)d_in[32];
    const float* bn_m      = (const float*)d_in[33];
    const float* bn_v      = (const float*)d_in[34];
    float* out = (float*)d_out;

    float* ws = (float*)d_ws;
    float* sm     = ws;  ws += 2*1024*128;
    float* sv     = ws;  ws += 2*1024*128;
    float* uraw_m = ws;  ws += 2*1024*256;
    float* zb_m   = ws;  ws += 2*1024*256;
    float* uc     = ws;  ws += 2*1024*256;     // mamba post-conv u
    float* uraw_v = ws;  ws += 2*1024*256;
    float* zb_v   = ws;  ws += 2*1024*256;
    float* usb    = ws;  ws += 2*4*1024*256;   // vss 4-direction sequences
    float* dt_m   = ws;  ws += 2*1024*256;
    float* yb_m   = ws;  ws += 2*1024*256;
    float* Pb_m   = ws;  ws += 2*NCH*256*16;
    float* Qb_m   = ws;  ws += 2*NCH*256*16;
    float* Bm_m   = ws;  ws += 2*1024*16;
    float* Cm_m   = ws;  ws += 2*1024*16;
    float* dt_v   = ws;  ws += 2*4*1024*256;
    float* yb_v   = ws;  ws += 2*4*1024*256;
    float* Pb_v   = ws;  ws += 2*4*NCH*256*16;
    float* Qb_v   = ws;  ws += 2*4*NCH*256*16;
    float* Bm_v   = ws;  ws += 2*4*1024*16;
    float* Cm_v   = ws;  ws += 2*4*1024*16;
    float* wtc    = ws;  ws += 256*256;
    unsigned short* Wr = (unsigned short*)ws;  ws += 576*1024/2;

    k_prep<<<640,   256, 0, stream>>>(proj1_w, proj2_w, wtc, fuse_w, Wr);
    k_proj<<<2*256, 256, 0, stream>>>(x, wtc, proj1_b, proj2_b, sm, sv);

    // first layer LN/in-proj
    k_lnmm2<<<512, 256, 0, stream>>>(sm, m_ln_w, m_ln_b, m_in_w, uraw_m, zb_m,
                                     sv, v_ln_w, v_ln_b, v_in_w, uraw_v, zb_v);

    for (int i = 0; i < 2; ++i){
        k_conv2 <<<4096, 256, 0, stream>>>(uraw_m, m_conv_w + (size_t)i*1024, m_conv_b + i*256, uc,
                                           uraw_v, v_conv_w + (size_t)i*2304, v_conv_b + i*256, usb);
        k_xsa2  <<<640,  256, 0, stream>>>(uc,  m_xproj_w + (size_t)i*10240,
                                           m_dt_w + (size_t)i*2048, m_dt_b + i*256,
                                           m_Alog + (size_t)i*4096,
                                           dt_m, Bm_m, Cm_m, Pb_m, Qb_m,
                                           usb, v_xproj_w + (size_t)i*40960,
                                           v_dt_w + (size_t)i*8192, v_dt_b + (size_t)i*1024,
                                           v_Alog + (size_t)i*16384,
                                           dt_v, Bm_v, Cm_v, Pb_v, Qb_v);
        k_scanP2<<<160,  256, 0, stream>>>(Pb_m, Qb_m, Pb_v, Qb_v);
        k_scanB2<<<640,  256, 0, stream>>>(dt_m, uc,  Bm_m, Cm_m, m_Alog + (size_t)i*4096,
                                           Pb_m, yb_m,
                                           dt_v, usb, Bm_v, Cm_v, v_Alog + (size_t)i*16384,
                                           Pb_v, yb_v);
        if (i == 0){
            k_epln2<<<512, 256, 0, stream>>>(yb_m, uc, zb_m, m_D, m_out_w, sm,
                                             yb_v, usb, zb_v, v_D,
                                             v_onorm_w, v_onorm_b, v_out_w, sv,
                                             m_ln_w + 128, m_ln_b + 128, m_in_w + 65536,
                                             uraw_m, zb_m,
                                             v_ln_w + 128, v_ln_b + 128, v_in_w + 65536,
                                             uraw_v, zb_v);
        } else {
            k_epi2 <<<512, 256, 0, stream>>>(yb_m, uc, zb_m, m_D + 256, m_out_w + 32768, sm,
                                             yb_v, usb, zb_v, v_D + 1024,
                                             v_onorm_w + 256, v_onorm_b + 256,
                                             v_out_w + 32768, sv);
        }
    }

    k_fgemm<<<4*32, 256, 0, stream>>>(Wr, sm, sv, fuse_b, bn_g, bn_b, bn_m, bn_v, out);
}

// Round 9
// 332.228 us; speedup vs baseline: 1.0571x; 1.0571x over previous
//
#include <hip/hip_runtime.h>
#include <math.h>

// Problem constants
// B=2, DIM=256, H=W=32, L=1024, HALF=128, DI=256, DS=16, DTR=8, DEPTH=2, K1=4
#define CH  16      // scan chunk length
#define NCH 64      // chunks per sequence (L / CH)

typedef __attribute__((ext_vector_type(8))) short bf16x8;
typedef __attribute__((ext_vector_type(4))) float f32x4;
typedef __attribute__((ext_vector_type(4))) unsigned int u32x4;

__device__ __forceinline__ float dev_silu(float x){ return x * (1.0f/(1.0f + __expf(-x))); }
__device__ __forceinline__ float dev_softplus(float x){ return fmaxf(x,0.0f) + log1pf(__expf(-fabsf(x))); }
__device__ __forceinline__ unsigned short dev_bf16(float f){
    unsigned int u = __float_as_uint(f);
    return (unsigned short)((u + 0x7fffu + ((u >> 16) & 1u)) >> 16);
}

// ====== prep: proj-weight transpose (blocks 0-63) + fuse-weight bf16 K-reorder (64-639) ======
// Wr[o][kp*256+c] = bf16(fw[o][c][kp]), kp = kh*3+kw
__global__ void __launch_bounds__(256)
k_prep(const float* __restrict__ w1, const float* __restrict__ w2, float* __restrict__ wtc,
       const float* __restrict__ fw, unsigned short* __restrict__ Wr)
{
    if (blockIdx.x < 64){
        int bc = blockIdx.x;           // 8 o-tiles x 8 c-tiles
        int ot = bc & 7, ct = bc >> 3;
        __shared__ float t[32][33];
        int col = threadIdx.x & 31, r8 = threadIdx.x >> 5;
        #pragma unroll
        for (int i = 0; i < 4; ++i){
            int r = i*8 + r8;
            int o = ot*32 + r;
            const float* src = (o < 128) ? (w1 + (size_t)o*256) : (w2 + (size_t)(o-128)*256);
            t[r][col] = src[ct*32 + col];
        }
        __syncthreads();
        #pragma unroll
        for (int i = 0; i < 4; ++i){
            int r = i*8 + r8;
            int c = ct*32 + r, o = ot*32 + col;
            wtc[(size_t)c*256 + o] = t[col][r];
        }
    } else {
        int t0 = ((blockIdx.x - 64)*256 + threadIdx.x)*4;   // 589824 elements total
        unsigned int r[4];
        #pragma unroll
        for (int j = 0; j < 4; ++j){
            int i = t0 + j;
            int o = i / 2304, kk = i - o*2304;
            int kp = kk >> 8, cc = kk & 255;
            r[j] = dev_bf16(fw[(size_t)o*2304 + cc*9 + kp]);
        }
        uint2 pk; pk.x = r[0] | (r[1] << 16); pk.y = r[2] | (r[3] << 16);
        *(uint2*)(Wr + t0) = pk;
    }
}

// ---- proj: block per (b, 4-l tile); coalesced transposed-weight reads ----
__global__ void __launch_bounds__(256)
k_proj(const float* __restrict__ x, const float* __restrict__ wtc,
       const float* __restrict__ b1, const float* __restrict__ b2,
       float* __restrict__ sm, float* __restrict__ sv)
{
    int blk = blockIdx.x;          // b*256 + lt
    int b = blk >> 8, l0 = (blk & 255) * 4;
    int tid = threadIdx.x;
    __shared__ float4 xs[256];
    xs[tid] = *(const float4*)(x + ((size_t)(b*256 + tid))*1024 + l0);
    __syncthreads();
    int o = tid & 127;
    float bias = (tid < 128) ? b1[o] : b2[o];
    float a0 = bias, a1 = bias, a2 = bias, a3 = bias;
    #pragma unroll 4
    for (int c = 0; c < 256; ++c){
        float wv = wtc[(size_t)c*256 + tid];
        float4 xv = xs[c];
        a0 = fmaf(wv, xv.x, a0);
        a1 = fmaf(wv, xv.y, a1);
        a2 = fmaf(wv, xv.z, a2);
        a3 = fmaf(wv, xv.w, a3);
    }
    float* dst = (tid < 128) ? sm : sv;
    size_t base = ((size_t)b*1024 + l0)*128 + o;
    dst[base      ] = a0;
    dst[base + 128] = a1;
    dst[base + 256] = a2;
    dst[base + 384] = a3;
}

// ================= LN(128) + matmul core (v supplied by caller) =================
__device__ __forceinline__ void lnmm_core(int bl0, float4 v,
    const float* __restrict__ lnw, const float* __restrict__ lnb,
    const float* __restrict__ inw, float* __restrict__ u, float* __restrict__ z,
    float (*hn)[132])
{
    int tid = threadIdx.x;
    int row = tid >> 5, lane = tid & 31;
    float a = v.x + v.y + v.z + v.w;
    float q = v.x*v.x + v.y*v.y + v.z*v.z + v.w*v.w;
    #pragma unroll
    for (int o = 16; o; o >>= 1){ a += __shfl_xor(a, o); q += __shfl_xor(q, o); }
    float mean = a * (1.0f/128.0f);
    float rs = rsqrtf(q * (1.0f/128.0f) - mean*mean + 1e-5f);
    float4 w4 = *(const float4*)(lnw + lane*4);
    float4 b4 = *(const float4*)(lnb + lane*4);
    float4 hv;
    hv.x = (v.x-mean)*rs*w4.x + b4.x;
    hv.y = (v.y-mean)*rs*w4.y + b4.y;
    hv.z = (v.z-mean)*rs*w4.z + b4.z;
    hv.w = (v.w-mean)*rs*w4.w + b4.w;
    *(float4*)&hn[row][lane*4] = hv;
    __syncthreads();
    float acc0[8] = {0,0,0,0,0,0,0,0};
    float acc1[8] = {0,0,0,0,0,0,0,0};
    for (int c = 0; c < 128; c += 4){
        float w0[4], w1[4];
        #pragma unroll
        for (int i = 0; i < 4; ++i){
            w0[i] = inw[(size_t)(c+i)*512 + tid];
            w1[i] = inw[(size_t)(c+i)*512 + tid + 256];
        }
        #pragma unroll
        for (int r = 0; r < 8; ++r){
            float4 h4 = *(const float4*)&hn[r][c];
            acc0[r] = fmaf(h4.x, w0[0], acc0[r]);
            acc0[r] = fmaf(h4.y, w0[1], acc0[r]);
            acc0[r] = fmaf(h4.z, w0[2], acc0[r]);
            acc0[r] = fmaf(h4.w, w0[3], acc0[r]);
            acc1[r] = fmaf(h4.x, w1[0], acc1[r]);
            acc1[r] = fmaf(h4.y, w1[1], acc1[r]);
            acc1[r] = fmaf(h4.z, w1[2], acc1[r]);
            acc1[r] = fmaf(h4.w, w1[3], acc1[r]);
        }
    }
    #pragma unroll
    for (int r = 0; r < 8; ++r){
        u[(size_t)(bl0 + r)*256 + tid] = acc0[r];
        z[(size_t)(bl0 + r)*256 + tid] = acc1[r];
    }
}

__global__ void __launch_bounds__(256)
k_lnmm2(const float* __restrict__ sm_, const float* __restrict__ mlnw, const float* __restrict__ mlnb,
        const float* __restrict__ minw, float* __restrict__ um, float* __restrict__ zm,
        const float* __restrict__ sv_, const float* __restrict__ vlnw, const float* __restrict__ vlnb,
        const float* __restrict__ vinw, float* __restrict__ uv, float* __restrict__ zv)
{
    __shared__ float hn[8][132];
    int tid = threadIdx.x;
    int row = tid >> 5, lane = tid & 31;
    if (blockIdx.x < 256){
        int bl0 = blockIdx.x*8;
        float4 v = *(const float4*)(sm_ + (size_t)(bl0 + row)*128 + lane*4);
        lnmm_core(bl0, v, mlnw, mlnb, minw, um, zm, hn);
    } else {
        int bl0 = (blockIdx.x-256)*8;
        float4 v = *(const float4*)(sv_ + (size_t)(bl0 + row)*128 + lane*4);
        lnmm_core(bl0, v, vlnw, vlnb, vinw, uv, zv, hn);
    }
}

// ================= conv: mamba causal K=4 (blocks 0-2047) + vss dw3x3+scatter =================
__global__ void __launch_bounds__(256)
k_conv2(const float* __restrict__ urm, const float* __restrict__ cwm, const float* __restrict__ cbm,
        float* __restrict__ uc,
        const float* __restrict__ urv, const float* __restrict__ cwv, const float* __restrict__ cbv,
        float* __restrict__ us)
{
    int d = threadIdx.x;
    if (blockIdx.x < 2048){
        int bl = blockIdx.x; int b = bl >> 10, l = bl & 1023;
        float acc = cbm[d];
        #pragma unroll
        for (int k = 0; k < 4; ++k){
            int lp = l - 3 + k;
            if (lp >= 0) acc = fmaf(urm[((size_t)(b<<10) + lp)*256 + d], cwm[d*4 + k], acc);
        }
        uc[(size_t)bl*256 + d] = dev_silu(acc);
    } else {
        int bl = blockIdx.x - 2048; int b = bl >> 10, l = bl & 1023;
        int h = l >> 5, w = l & 31;
        float acc = cbv[d];
        #pragma unroll
        for (int kh = 0; kh < 3; ++kh){
            int hh = h + kh - 1; if (hh < 0 || hh > 31) continue;
            #pragma unroll
            for (int kw = 0; kw < 3; ++kw){
                int ww = w + kw - 1; if (ww < 0 || ww > 31) continue;
                acc = fmaf(urv[((size_t)(b<<10) + (hh<<5) + ww)*256 + d], cwv[d*9 + kh*3 + kw], acc);
            }
        }
        float v = dev_silu(acc);
        int l1 = (w<<5) + h;
        size_t base = (size_t)b*4*1024*256;
        us[base + ((size_t)0*1024 + l        )*256 + d] = v;
        us[base + ((size_t)1*1024 + l1       )*256 + d] = v;
        us[base + ((size_t)2*1024 + (1023-l ))*256 + d] = v;
        us[base + ((size_t)3*1024 + (1023-l1))*256 + d] = v;
    }
}

// ================= xproj: 4 l-positions per block (R7-verified) =================
__device__ __forceinline__ void xproj_body(size_t idx0, int k, const float* __restrict__ u,
    const float* __restrict__ xw, const float* __restrict__ dtw, const float* __restrict__ dtb,
    float* __restrict__ dt, float* __restrict__ Bm, float* __restrict__ Cm)
{
    int tid = threadIdx.x;
    __shared__ float ursh[4][256];
    __shared__ float dbc[4][44];
    #pragma unroll
    for (int p = 0; p < 4; ++p)
        ursh[p][tid] = u[(idx0 + p)*256 + tid];
    __syncthreads();
    if (tid < 160){
        int r = tid % 40, p = tid / 40;
        const float* xwc = xw + (size_t)k*256*40 + r;
        float a0 = 0.f, a1 = 0.f;
        for (int c = 0; c < 128; ++c){
            a0 = fmaf(ursh[p][c],       xwc[(size_t)c*40],       a0);
            a1 = fmaf(ursh[p][c + 128], xwc[(size_t)(c+128)*40], a1);
        }
        dbc[p][r] = a0 + a1;
    }
    __syncthreads();
    const float* dtwk = dtw + (size_t)k*8*256;
    float bias = dtb[k*256 + tid];
    float wv[8];
    #pragma unroll
    for (int r = 0; r < 8; ++r) wv[r] = dtwk[r*256 + tid];
    #pragma unroll
    for (int p = 0; p < 4; ++p){
        float a = bias;
        #pragma unroll
        for (int r = 0; r < 8; ++r) a = fmaf(dbc[p][r], wv[r], a);
        dt[(idx0 + p)*256 + tid] = dev_softplus(a);
    }
    if (tid < 128){
        int p = tid >> 5, j = tid & 31;
        if (j < 16) Bm[(idx0 + p)*16 + j]        = dbc[p][8 + j];
        else        Cm[(idx0 + p)*16 + (j - 16)] = dbc[p][8 + j];
    }
}

__global__ void __launch_bounds__(256)
k_xproj2(const float* __restrict__ um, const float* __restrict__ mxw, const float* __restrict__ mdtw,
         const float* __restrict__ mdtb, float* __restrict__ dtm, float* __restrict__ Bmm,
         float* __restrict__ Cmm,
         const float* __restrict__ uv, const float* __restrict__ vxw, const float* __restrict__ vdtw,
         const float* __restrict__ vdtb, float* __restrict__ dtv, float* __restrict__ Bmv,
         float* __restrict__ Cmv)
{
    if (blockIdx.x < 512){
        int bk = blockIdx.x >> 8;
        size_t idx0 = (size_t)bk*1024 + (blockIdx.x & 255)*4;
        xproj_body(idx0, 0, um, mxw, mdtw, mdtb, dtm, Bmm, Cmm);
    } else {
        int blk = blockIdx.x - 512;
        int bk = blk >> 8;
        size_t idx0 = (size_t)bk*1024 + (blk & 255)*4;
        xproj_body(idx0, bk & 3, uv, vxw, vdtw, vdtb, dtv, Bmv, Cmv);
    }
}

// ================= scan pass A (R7-verified) =================
__device__ __forceinline__ void scanA_body(int bk, int c, int k, const float* __restrict__ dt,
    const float* __restrict__ u, const float* __restrict__ Bm, const float* __restrict__ Alog,
    float* __restrict__ Pb, float* __restrict__ Qb)
{
    int d = threadIdx.x;
    __shared__ float Bsh[CH][16];
    {
        int j = threadIdx.x >> 4, s = threadIdx.x & 15;
        Bsh[j][s] = Bm[((size_t)bk*1024 + c*CH + j)*16 + s];
    }
    float dtv[CH], duv[CH];
    size_t base = ((size_t)bk*1024 + c*CH)*256 + d;
    #pragma unroll
    for (int j = 0; j < CH; ++j){
        float a = dt[base + (size_t)j*256];
        float b = u [base + (size_t)j*256];
        dtv[j] = a; duv[j] = a*b;
    }
    float A[16];
    const float4* Ap = (const float4*)(Alog + ((size_t)k*256 + d)*16);
    #pragma unroll
    for (int q = 0; q < 4; ++q){
        float4 v = Ap[q];
        A[q*4+0] = -__expf(v.x); A[q*4+1] = -__expf(v.y);
        A[q*4+2] = -__expf(v.z); A[q*4+3] = -__expf(v.w);
    }
    __syncthreads();
    float Q[16];
    #pragma unroll
    for (int s = 0; s < 16; ++s) Q[s] = 0.f;
    float S = 0.f;
    #pragma unroll
    for (int j = 0; j < CH; ++j){
        S += dtv[j];
        #pragma unroll
        for (int s = 0; s < 16; ++s){
            float av = __expf(dtv[j]*A[s]);
            Q[s] = fmaf(av, Q[s], duv[j]*Bsh[j][s]);
        }
    }
    size_t oidx = ((size_t)(bk*NCH + c)*256 + d)*16;
    float4* Pp = (float4*)(Pb + oidx);
    float4* Qp = (float4*)(Qb + oidx);
    #pragma unroll
    for (int q = 0; q < 4; ++q){
        float4 pv, qv;
        pv.x = __expf(S*A[q*4+0]); pv.y = __expf(S*A[q*4+1]);
        pv.z = __expf(S*A[q*4+2]); pv.w = __expf(S*A[q*4+3]);
        qv.x = Q[q*4+0]; qv.y = Q[q*4+1]; qv.z = Q[q*4+2]; qv.w = Q[q*4+3];
        Pp[q] = pv; Qp[q] = qv;
    }
}

__global__ void __launch_bounds__(256)
k_scanA2(const float* __restrict__ dtm, const float* __restrict__ um, const float* __restrict__ Bmm,
         const float* __restrict__ mAlog, float* __restrict__ Pbm, float* __restrict__ Qbm,
         const float* __restrict__ dtv, const float* __restrict__ uv, const float* __restrict__ Bmv,
         const float* __restrict__ vAlog, float* __restrict__ Pbv, float* __restrict__ Qbv)
{
    if (blockIdx.x < 128){
        int blk = blockIdx.x;
        scanA_body(blk >> 6, blk & (NCH-1), 0, dtm, um, Bmm, mAlog, Pbm, Qbm);
    } else {
        int blk = blockIdx.x - 128;
        int bk = blk >> 6;
        scanA_body(bk, blk & (NCH-1), bk & 3, dtv, uv, Bmv, vAlog, Pbv, Qbv);
    }
}

// ================= scan pass P =================
__device__ __forceinline__ void scanP_body(int bk, int dg, float* __restrict__ Pb,
                                           const float* __restrict__ Qb)
{
    int tid = threadIdx.x;
    size_t idx0 = (size_t)bk*NCH*4096 + dg*256 + tid;
    float Pv[NCH], Qv[NCH];
    #pragma unroll
    for (int c = 0; c < NCH; ++c){
        Pv[c] = Pb[idx0 + (size_t)c*4096];
        Qv[c] = Qb[idx0 + (size_t)c*4096];
    }
    float h = 0.f;
    #pragma unroll
    for (int c = 0; c < NCH; ++c){
        Pb[idx0 + (size_t)c*4096] = h;
        h = fmaf(Pv[c], h, Qv[c]);
    }
}

__global__ void __launch_bounds__(256)
k_scanP2(float* __restrict__ Pbm, const float* __restrict__ Qbm,
         float* __restrict__ Pbv, const float* __restrict__ Qbv)
{
    if (blockIdx.x < 32) scanP_body(blockIdx.x >> 4, blockIdx.x & 15, Pbm, Qbm);
    else { int blk = blockIdx.x - 32; scanP_body(blk >> 4, blk & 15, Pbv, Qbv); }
}

// ================= scan pass B =================
__device__ __forceinline__ void scanB_body(int bk, int c, int k, const float* __restrict__ dt,
    const float* __restrict__ u, const float* __restrict__ Bm, const float* __restrict__ Cm,
    const float* __restrict__ Alog, const float* __restrict__ Hb, float* __restrict__ y)
{
    int d = threadIdx.x;
    __shared__ float Bsh[CH][16], Csh[CH][16];
    {
        int j = threadIdx.x >> 4, s = threadIdx.x & 15;
        size_t bi = ((size_t)bk*1024 + c*CH + j)*16 + s;
        Bsh[j][s] = Bm[bi];
        Csh[j][s] = Cm[bi];
    }
    float dtv[CH], duv[CH];
    size_t base = ((size_t)bk*1024 + c*CH)*256 + d;
    #pragma unroll
    for (int j = 0; j < CH; ++j){
        float a = dt[base + (size_t)j*256];
        float b = u [base + (size_t)j*256];
        dtv[j] = a; duv[j] = a*b;
    }
    float A[16];
    const float4* Ap = (const float4*)(Alog + ((size_t)k*256 + d)*16);
    #pragma unroll
    for (int q = 0; q < 4; ++q){
        float4 v = Ap[q];
        A[q*4+0] = -__expf(v.x); A[q*4+1] = -__expf(v.y);
        A[q*4+2] = -__expf(v.z); A[q*4+3] = -__expf(v.w);
    }
    float h[16];
    const float4* Hp = (const float4*)(Hb + ((size_t)(bk*NCH + c)*256 + d)*16);
    #pragma unroll
    for (int q = 0; q < 4; ++q){
        float4 v = Hp[q];
        h[q*4+0] = v.x; h[q*4+1] = v.y; h[q*4+2] = v.z; h[q*4+3] = v.w;
    }
    __syncthreads();
    float* yp = y + base;
    #pragma unroll
    for (int j = 0; j < CH; ++j){
        float py = 0.f;
        #pragma unroll
        for (int s = 0; s < 16; ++s){
            float av = __expf(dtv[j]*A[s]);
            h[s] = fmaf(av, h[s], duv[j]*Bsh[j][s]);
            py = fmaf(h[s], Csh[j][s], py);
        }
        yp[(size_t)j*256] = py;
    }
}

__global__ void __launch_bounds__(256)
k_scanB2(const float* __restrict__ dtm, const float* __restrict__ um, const float* __restrict__ Bmm,
         const float* __restrict__ Cmm, const float* __restrict__ mAlog,
         const float* __restrict__ Hbm, float* __restrict__ ym,
         const float* __restrict__ dtv, const float* __restrict__ uv, const float* __restrict__ Bmv,
         const float* __restrict__ Cmv, const float* __restrict__ vAlog,
         const float* __restrict__ Hbv, float* __restrict__ yv)
{
    if (blockIdx.x < 128){
        int blk = blockIdx.x;
        scanB_body(blk >> 6, blk & (NCH-1), 0, dtm, um, Bmm, Cmm, mAlog, Hbm, ym);
    } else {
        int blk = blockIdx.x - 128;
        int bk = blk >> 6;
        scanB_body(bk, blk & (NCH-1), bk & 3, dtv, uv, Bmv, Cmv, vAlog, Hbv, yv);
    }
}

// ================= epilogues (write updated rows to LDS for optional fused LN) ========
__device__ __forceinline__ void mout_body(int bl0, const float* __restrict__ y,
    const float* __restrict__ uc, const float* __restrict__ z, const float* __restrict__ Dp,
    const float* __restrict__ ow, float* __restrict__ sm, float* __restrict__ srowp)
{
    int tid = threadIdx.x;
    int row = tid >> 5, c0 = (tid & 31) * 8;
    __shared__ float gld[8][264];
    size_t base = (size_t)(bl0 + row)*256 + c0;
    #pragma unroll
    for (int i = 0; i < 8; i += 4){
        float4 yv = *(const float4*)(y + base + i);
        float4 uv = *(const float4*)(uc + base + i);
        float4 zv = *(const float4*)(z + base + i);
        float4 dv = *(const float4*)(Dp + c0 + i);
        gld[row][c0+i+0] = (yv.x + uv.x*dv.x) * dev_silu(zv.x);
        gld[row][c0+i+1] = (yv.y + uv.y*dv.y) * dev_silu(zv.y);
        gld[row][c0+i+2] = (yv.z + uv.z*dv.z) * dev_silu(zv.z);
        gld[row][c0+i+3] = (yv.w + uv.w*dv.w) * dev_silu(zv.w);
    }
    __syncthreads();
    int o = tid & 127, rg = tid >> 7;
    float acc[4] = {0,0,0,0};
    for (int c = 0; c < 256; c += 4){
        float w[4];
        #pragma unroll
        for (int i = 0; i < 4; ++i) w[i] = ow[(size_t)(c+i)*128 + o];
        #pragma unroll
        for (int r = 0; r < 4; ++r){
            float4 h4 = *(const float4*)&gld[rg*4 + r][c];
            acc[r] = fmaf(h4.x, w[0], acc[r]);
            acc[r] = fmaf(h4.y, w[1], acc[r]);
            acc[r] = fmaf(h4.z, w[2], acc[r]);
            acc[r] = fmaf(h4.w, w[3], acc[r]);
        }
    }
    #pragma unroll
    for (int r = 0; r < 4; ++r){
        size_t gi = (size_t)(bl0 + rg*4 + r)*128 + o;
        float nv = sm[gi] + acc[r];
        sm[gi] = nv;
        srowp[(rg*4 + r)*128 + o] = nv;
    }
}

__device__ __forceinline__ void vcomb_body(int blk, const float* __restrict__ y,
    const float* __restrict__ us, const float* __restrict__ z, const float* __restrict__ Dp,
    const float* __restrict__ onw, const float* __restrict__ onb, const float* __restrict__ ow,
    float* __restrict__ sv, float* __restrict__ srowp)
{
    int b = blk >> 7;
    int l0 = (blk & 127) * 8;
    int tid = threadIdx.x;
    int row = tid >> 5, c0 = (tid & 31) * 8;
    int l = l0 + row;
    int h = l >> 5, w = l & 31;
    int l1 = (w<<5) + h, l2 = 1023 - l, l3 = 1023 - l1;
    size_t base = (size_t)b*4*1024*256;
    size_t i0 = base + ((size_t)0*1024 + l )*256 + c0;
    size_t i1 = base + ((size_t)1*1024 + l1)*256 + c0;
    size_t i2 = base + ((size_t)2*1024 + l2)*256 + c0;
    size_t i3 = base + ((size_t)3*1024 + l3)*256 + c0;
    float t[8];
    #pragma unroll
    for (int i = 0; i < 8; i += 4){
        float4 yv = *(const float4*)(y + i0 + i);
        float4 uv = *(const float4*)(us + i0 + i);
        float4 dv = *(const float4*)(Dp + 0*256 + c0 + i);
        t[i+0] = yv.x + uv.x*dv.x; t[i+1] = yv.y + uv.y*dv.y;
        t[i+2] = yv.z + uv.z*dv.z; t[i+3] = yv.w + uv.w*dv.w;
    }
    #pragma unroll
    for (int i = 0; i < 8; i += 4){
        float4 yv = *(const float4*)(y + i1 + i);
        float4 uv = *(const float4*)(us + i1 + i);
        float4 dv = *(const float4*)(Dp + 1*256 + c0 + i);
        t[i+0] += yv.x + uv.x*dv.x; t[i+1] += yv.y + uv.y*dv.y;
        t[i+2] += yv.z + uv.z*dv.z; t[i+3] += yv.w + uv.w*dv.w;
    }
    #pragma unroll
    for (int i = 0; i < 8; i += 4){
        float4 yv = *(const float4*)(y + i2 + i);
        float4 uv = *(const float4*)(us + i2 + i);
        float4 dv = *(const float4*)(Dp + 2*256 + c0 + i);
        t[i+0] += yv.x + uv.x*dv.x; t[i+1] += yv.y + uv.y*dv.y;
        t[i+2] += yv.z + uv.z*dv.z; t[i+3] += yv.w + uv.w*dv.w;
    }
    #pragma unroll
    for (int i = 0; i < 8; i += 4){
        float4 yv = *(const float4*)(y + i3 + i);
        float4 uv = *(const float4*)(us + i3 + i);
        float4 dv = *(const float4*)(Dp + 3*256 + c0 + i);
        t[i+0] += yv.x + uv.x*dv.x; t[i+1] += yv.y + uv.y*dv.y;
        t[i+2] += yv.z + uv.z*dv.z; t[i+3] += yv.w + uv.w*dv.w;
    }
    float a = 0.f, q = 0.f;
    #pragma unroll
    for (int i = 0; i < 8; ++i){ a += t[i]; q += t[i]*t[i]; }
    #pragma unroll
    for (int o = 16; o; o >>= 1){ a += __shfl_xor(a, o); q += __shfl_xor(q, o); }
    float mean = a * (1.0f/256.0f);
    float rs = rsqrtf(q * (1.0f/256.0f) - mean*mean + 1e-5f);
    __shared__ float gld[8][264];
    size_t zbase = (size_t)(b*1024 + l)*256 + c0;
    #pragma unroll
    for (int i = 0; i < 8; i += 4){
        float4 wv = *(const float4*)(onw + c0 + i);
        float4 bv = *(const float4*)(onb + c0 + i);
        float4 zv = *(const float4*)(z + zbase + i);
        gld[row][c0+i+0] = ((t[i+0]-mean)*rs*wv.x + bv.x) * dev_silu(zv.x);
        gld[row][c0+i+1] = ((t[i+1]-mean)*rs*wv.y + bv.y) * dev_silu(zv.y);
        gld[row][c0+i+2] = ((t[i+2]-mean)*rs*wv.z + bv.z) * dev_silu(zv.z);
        gld[row][c0+i+3] = ((t[i+3]-mean)*rs*wv.w + bv.w) * dev_silu(zv.w);
    }
    __syncthreads();
    int o = tid & 127, rg = tid >> 7;
    float acc[4] = {0,0,0,0};
    for (int c = 0; c < 256; c += 4){
        float wv[4];
        #pragma unroll
        for (int i = 0; i < 4; ++i) wv[i] = ow[(size_t)(c+i)*128 + o];
        #pragma unroll
        for (int r = 0; r < 4; ++r){
            float4 h4 = *(const float4*)&gld[rg*4 + r][c];
            acc[r] = fmaf(h4.x, wv[0], acc[r]);
            acc[r] = fmaf(h4.y, wv[1], acc[r]);
            acc[r] = fmaf(h4.z, wv[2], acc[r]);
            acc[r] = fmaf(h4.w, wv[3], acc[r]);
        }
    }
    #pragma unroll
    for (int r = 0; r < 4; ++r){
        size_t gi = (size_t)(b*1024 + l0 + rg*4 + r)*128 + o;
        float nv = sv[gi] + acc[r];
        sv[gi] = nv;
        srowp[(rg*4 + r)*128 + o] = nv;
    }
}

// final-layer epilogue (no fused LN)
__global__ void __launch_bounds__(256)
k_epi2(const float* __restrict__ ym, const float* __restrict__ uc, const float* __restrict__ zm,
       const float* __restrict__ mD, const float* __restrict__ mow, float* __restrict__ sm,
       const float* __restrict__ yv, const float* __restrict__ us, const float* __restrict__ zv,
       const float* __restrict__ vD, const float* __restrict__ onw, const float* __restrict__ onb,
       const float* __restrict__ vow, float* __restrict__ sv)
{
    __shared__ float srow[8][128];
    if (blockIdx.x < 256) mout_body(blockIdx.x*8, ym, uc, zm, mD, mow, sm, &srow[0][0]);
    else                  vcomb_body(blockIdx.x-256, yv, us, zv, vD, onw, onb, vow, sv, &srow[0][0]);
}

// epilogue + next-layer LN/in-proj fused
__global__ void __launch_bounds__(256)
k_epln2(const float* __restrict__ ym, const float* __restrict__ uc, const float* __restrict__ zm,
        const float* __restrict__ mD, const float* __restrict__ mow, float* __restrict__ sm,
        const float* __restrict__ yv, const float* __restrict__ us, const float* __restrict__ zv,
        const float* __restrict__ vD, const float* __restrict__ onw, const float* __restrict__ onb,
        const float* __restrict__ vow, float* __restrict__ sv,
        const float* __restrict__ mlnw, const float* __restrict__ mlnb, const float* __restrict__ minw,
        float* __restrict__ um_o, float* __restrict__ zm_o,
        const float* __restrict__ vlnw, const float* __restrict__ vlnb, const float* __restrict__ vinw,
        float* __restrict__ uv_o, float* __restrict__ zv_o)
{
    __shared__ float srow[8][128];
    __shared__ float hn[8][132];
    int tid = threadIdx.x;
    int row = tid >> 5, lane = tid & 31;
    if (blockIdx.x < 256){
        int bl0 = blockIdx.x*8;
        mout_body(bl0, ym, uc, zm, mD, mow, sm, &srow[0][0]);
        __syncthreads();
        float4 v = *(const float4*)&srow[row][lane*4];
        lnmm_core(bl0, v, mlnw, mlnb, minw, um_o, zm_o, hn);
    } else {
        int blk = blockIdx.x - 256;
        int bl0 = (blk >> 7)*1024 + (blk & 127)*8;
        vcomb_body(blk, yv, us, zv, vD, onw, onb, vow, sv, &srow[0][0]);
        __syncthreads();
        float4 v = *(const float4*)&srow[row][lane*4];
        lnmm_core(bl0, v, vlnw, vlnb, vinw, uv_o, zv_o, hn);
    }
}

// ---- bf16 MFMA GEMM with inline im2col (K reordered: kp major, c minor) ----
__global__ void __launch_bounds__(256)
k_fgemm(const unsigned short* __restrict__ Wr, const float* __restrict__ sm,
        const float* __restrict__ sv, const float* __restrict__ fb,
        const float* __restrict__ bg, const float* __restrict__ bb,
        const float* __restrict__ bm, const float* __restrict__ bv, float* __restrict__ out)
{
    int o0 = (blockIdx.x & 3) * 64;
    int n0 = (blockIdx.x >> 2) * 64;
    int tid = threadIdx.x, lane = tid & 63, wid = tid >> 6;
    int wm = (wid >> 1) * 32, wn = (wid & 1) * 32;
    __shared__ unsigned short sA[64*40];
    __shared__ unsigned short sB[64*40];
    f32x4 acc[2][2] = {};
    int srow = tid >> 2, scol = (tid & 3) * 8;
    const u32x4* gA = (const u32x4*)(Wr + (size_t)(o0 + srow)*2304 + scol);
    u32x4* wA = (u32x4*)(sA + srow*40 + scol);
    u32x4* wB = (u32x4*)(sB + srow*40 + scol);
    int n = n0 + srow; int b = n >> 10, p = n & 1023, h = p >> 5, w = p & 31;
    int fr = lane & 15, fk = (lane >> 4) * 8;
    const unsigned short* rA0 = sA + (wm + fr)*40 + fk;
    const unsigned short* rA1 = sA + (wm + 16 + fr)*40 + fk;
    const unsigned short* rB0 = sB + (wn + fr)*40 + fk;
    const unsigned short* rB1 = sB + (wn + 16 + fr)*40 + fk;
    for (int kt = 0; kt < 72; ++kt){
        u32x4 va = gA[kt*4];
        int kp = kt >> 3, c0 = (kt & 7) * 32;
        int kh = kp / 3, kw = kp - kh*3;
        int hh = h + kh - 1, ww = w + kw - 1;
        int cg = c0 + scol;
        float4 v0 = make_float4(0.f,0.f,0.f,0.f), v1 = v0;
        if ((unsigned)hh < 32u && (unsigned)ww < 32u){
            const float* sp = ((cg < 128) ? sm : sv)
                            + ((size_t)(b*1024 + (hh<<5) + ww))*128 + (cg & 127);
            v0 = *(const float4*)sp;
            v1 = *(const float4*)(sp + 4);
        }
        u32x4 vb;
        vb.x = dev_bf16(v0.x) | ((unsigned)dev_bf16(v0.y) << 16);
        vb.y = dev_bf16(v0.z) | ((unsigned)dev_bf16(v0.w) << 16);
        vb.z = dev_bf16(v1.x) | ((unsigned)dev_bf16(v1.y) << 16);
        vb.w = dev_bf16(v1.z) | ((unsigned)dev_bf16(v1.w) << 16);
        __syncthreads();
        *wA = va; *wB = vb;
        __syncthreads();
        bf16x8 a0 = *(const bf16x8*)rA0;
        bf16x8 a1 = *(const bf16x8*)rA1;
        bf16x8 b0 = *(const bf16x8*)rB0;
        bf16x8 b1 = *(const bf16x8*)rB1;
        acc[0][0] = __builtin_amdgcn_mfma_f32_16x16x32_bf16(a0, b0, acc[0][0], 0, 0, 0);
        acc[0][1] = __builtin_amdgcn_mfma_f32_16x16x32_bf16(a0, b1, acc[0][1], 0, 0, 0);
        acc[1][0] = __builtin_amdgcn_mfma_f32_16x16x32_bf16(a1, b0, acc[1][0], 0, 0, 0);
        acc[1][1] = __builtin_amdgcn_mfma_f32_16x16x32_bf16(a1, b1, acc[1][1], 0, 0, 0);
    }
    #pragma unroll
    for (int i = 0; i < 2; ++i){
        int ob = o0 + wm + i*16 + (lane >> 4) * 4;
        #pragma unroll
        for (int j = 0; j < 2; ++j){
            int nn = n0 + wn + j*16 + (lane & 15);
            int bb_ = nn >> 10, pp = nn & 1023;
            #pragma unroll
            for (int q = 0; q < 4; ++q){
                int o = ob + q;
                float v = acc[i][j][q] + fb[o];
                v = (v - bm[o]) * rsqrtf(bv[o] + 1e-5f) * bg[o] + bb[o];
                out[((size_t)(bb_*256 + o))*1024 + pp] = fmaxf(v, 0.f);
            }
        }
    }
}

extern "C" void kernel_launch(void* const* d_in, const int* in_sizes, int n_in,
                              void* d_out, int out_size, void* d_ws, size_t ws_size,
                              hipStream_t stream)
{
    const float* x         = (const float*)d_in[0];
    const float* proj1_w   = (const float*)d_in[1];
    const float* proj1_b   = (const float*)d_in[2];
    const float* proj2_w   = (const float*)d_in[3];
    const float* proj2_b   = (const float*)d_in[4];
    const float* m_ln_w    = (const float*)d_in[5];
    const float* m_ln_b    = (const float*)d_in[6];
    const float* m_in_w    = (const float*)d_in[7];
    const float* m_conv_w  = (const float*)d_in[8];
    const float* m_conv_b  = (const float*)d_in[9];
    const float* m_xproj_w = (const float*)d_in[10];
    const float* m_dt_w    = (const float*)d_in[11];
    const float* m_dt_b    = (const float*)d_in[12];
    const float* m_Alog    = (const float*)d_in[13];
    const float* m_D       = (const float*)d_in[14];
    const float* m_out_w   = (const float*)d_in[15];
    const float* v_ln_w    = (const float*)d_in[16];
    const float* v_ln_b    = (const float*)d_in[17];
    const float* v_in_w    = (const float*)d_in[18];
    const float* v_conv_w  = (const float*)d_in[19];
    const float* v_conv_b  = (const float*)d_in[20];
    const float* v_xproj_w = (const float*)d_in[21];
    const float* v_dt_w    = (const float*)d_in[22];
    const float* v_dt_b    = (const float*)d_in[23];
    const float* v_Alog    = (const float*)d_in[24];
    const float* v_D       = (const float*)d_in[25];
    const float* v_onorm_w = (const float*)d_in[26];
    const float* v_onorm_b = (const float*)d_in[27];
    const float* v_out_w   = (const float*)d_in[28];
    const float* fuse_w    = (const float*)d_in[29];
    const float* fuse_b    = (const float*)d_in[30];
    const float* bn_g      = (const float*)d_in[31];
    const float* bn_b      = (const float*)d_in[32];
    const float* bn_m      = (const float*)d_in[33];
    const float* bn_v      = (const float*)d_in[34];
    float* out = (float*)d_out;

    float* ws = (float*)d_ws;
    float* sm     = ws;  ws += 2*1024*128;
    float* sv     = ws;  ws += 2*1024*128;
    float* uraw_m = ws;  ws += 2*1024*256;
    float* zb_m   = ws;  ws += 2*1024*256;
    float* uc     = ws;  ws += 2*1024*256;     // mamba post-conv u
    float* uraw_v = ws;  ws += 2*1024*256;
    float* zb_v   = ws;  ws += 2*1024*256;
    float* usb    = ws;  ws += 2*4*1024*256;   // vss 4-direction sequences
    float* dt_m   = ws;  ws += 2*1024*256;
    float* yb_m   = ws;  ws += 2*1024*256;
    float* Pb_m   = ws;  ws += 2*NCH*256*16;
    float* Qb_m   = ws;  ws += 2*NCH*256*16;
    float* Bm_m   = ws;  ws += 2*1024*16;
    float* Cm_m   = ws;  ws += 2*1024*16;
    float* dt_v   = ws;  ws += 2*4*1024*256;
    float* yb_v   = ws;  ws += 2*4*1024*256;
    float* Pb_v   = ws;  ws += 2*4*NCH*256*16;
    float* Qb_v   = ws;  ws += 2*4*NCH*256*16;
    float* Bm_v   = ws;  ws += 2*4*1024*16;
    float* Cm_v   = ws;  ws += 2*4*1024*16;
    float* wtc    = ws;  ws += 256*256;
    unsigned short* Wr = (unsigned short*)ws;  ws += 576*1024/2;

    k_prep<<<640,   256, 0, stream>>>(proj1_w, proj2_w, wtc, fuse_w, Wr);
    k_proj<<<2*256, 256, 0, stream>>>(x, wtc, proj1_b, proj2_b, sm, sv);

    // first layer LN/in-proj
    k_lnmm2<<<512, 256, 0, stream>>>(sm, m_ln_w, m_ln_b, m_in_w, uraw_m, zb_m,
                                     sv, v_ln_w, v_ln_b, v_in_w, uraw_v, zb_v);

    for (int i = 0; i < 2; ++i){
        k_conv2 <<<4096, 256, 0, stream>>>(uraw_m, m_conv_w + (size_t)i*1024, m_conv_b + i*256, uc,
                                           uraw_v, v_conv_w + (size_t)i*2304, v_conv_b + i*256, usb);
        k_xproj2<<<2560, 256, 0, stream>>>(uc,  m_xproj_w + (size_t)i*10240,
                                           m_dt_w + (size_t)i*2048, m_dt_b + i*256,
                                           dt_m, Bm_m, Cm_m,
                                           usb, v_xproj_w + (size_t)i*40960,
                                           v_dt_w + (size_t)i*8192, v_dt_b + (size_t)i*1024,
                                           dt_v, Bm_v, Cm_v);
        k_scanA2<<<640,  256, 0, stream>>>(dt_m, uc,  Bm_m, m_Alog + (size_t)i*4096,  Pb_m, Qb_m,
                                           dt_v, usb, Bm_v, v_Alog + (size_t)i*16384, Pb_v, Qb_v);
        k_scanP2<<<160,  256, 0, stream>>>(Pb_m, Qb_m, Pb_v, Qb_v);
        k_scanB2<<<640,  256, 0, stream>>>(dt_m, uc,  Bm_m, Cm_m, m_Alog + (size_t)i*4096,
                                           Pb_m, yb_m,
                                           dt_v, usb, Bm_v, Cm_v, v_Alog + (size_t)i*16384,
                                           Pb_v, yb_v);
        if (i == 0){
            k_epln2<<<512, 256, 0, stream>>>(yb_m, uc, zb_m, m_D, m_out_w, sm,
                                             yb_v, usb, zb_v, v_D,
                                             v_onorm_w, v_onorm_b, v_out_w, sv,
                                             m_ln_w + 128, m_ln_b + 128, m_in_w + 65536,
                                             uraw_m, zb_m,
                                             v_ln_w + 128, v_ln_b + 128, v_in_w + 65536,
                                             uraw_v, zb_v);
        } else {
            k_epi2 <<<512, 256, 0, stream>>>(yb_m, uc, zb_m, m_D + 256, m_out_w + 32768, sm,
                                             yb_v, usb, zb_v, v_D + 1024,
                                             v_onorm_w + 256, v_onorm_b + 256,
                                             v_out_w + 32768, sv);
        }
    }

    k_fgemm<<<4*32, 256, 0, stream>>>(Wr, sm, sv, fuse_b, bn_g, bn_b, bn_m, bn_v, out);
}

// Round 10
// 295.590 us; speedup vs baseline: 1.1881x; 1.1239x over previous
//
#include <hip/hip_runtime.h>
#include <math.h>

// Problem constants
// B=2, DIM=256, H=W=32, L=1024, HALF=128, DI=256, DS=16, DTR=8, DEPTH=2, K1=4
#define CH  16      // scan chunk length
#define NCH 64      // chunks per sequence (L / CH)

typedef __attribute__((ext_vector_type(8))) short bf16x8;
typedef __attribute__((ext_vector_type(4))) float f32x4;
typedef __attribute__((ext_vector_type(4))) unsigned int u32x4;

__device__ __forceinline__ float dev_silu(float x){ return x * (1.0f/(1.0f + __expf(-x))); }
__device__ __forceinline__ float dev_softplus(float x){ return fmaxf(x,0.0f) + log1pf(__expf(-fabsf(x))); }
__device__ __forceinline__ unsigned short dev_bf16(float f){
    unsigned int u = __float_as_uint(f);
    return (unsigned short)((u + 0x7fffu + ((u >> 16) & 1u)) >> 16);
}

// ====== prep: proj-weight transpose (blocks 0-63) + fuse-weight bf16 K-reorder (64-639) ======
// Wr[o][kp*256+c] = bf16(fw[o][c][kp]), kp = kh*3+kw
__global__ void __launch_bounds__(256)
k_prep(const float* __restrict__ w1, const float* __restrict__ w2, float* __restrict__ wtc,
       const float* __restrict__ fw, unsigned short* __restrict__ Wr)
{
    if (blockIdx.x < 64){
        int bc = blockIdx.x;           // 8 o-tiles x 8 c-tiles
        int ot = bc & 7, ct = bc >> 3;
        __shared__ float t[32][33];
        int col = threadIdx.x & 31, r8 = threadIdx.x >> 5;
        #pragma unroll
        for (int i = 0; i < 4; ++i){
            int r = i*8 + r8;
            int o = ot*32 + r;
            const float* src = (o < 128) ? (w1 + (size_t)o*256) : (w2 + (size_t)(o-128)*256);
            t[r][col] = src[ct*32 + col];
        }
        __syncthreads();
        #pragma unroll
        for (int i = 0; i < 4; ++i){
            int r = i*8 + r8;
            int c = ct*32 + r, o = ot*32 + col;
            wtc[(size_t)c*256 + o] = t[col][r];
        }
    } else {
        int t0 = ((blockIdx.x - 64)*256 + threadIdx.x)*4;   // 589824 elements total
        unsigned int r[4];
        #pragma unroll
        for (int j = 0; j < 4; ++j){
            int i = t0 + j;
            int o = i / 2304, kk = i - o*2304;
            int kp = kk >> 8, cc = kk & 255;
            r[j] = dev_bf16(fw[(size_t)o*2304 + cc*9 + kp]);
        }
        uint2 pk; pk.x = r[0] | (r[1] << 16); pk.y = r[2] | (r[3] << 16);
        *(uint2*)(Wr + t0) = pk;
    }
}

// ---- proj: block per (b, 4-l tile); coalesced transposed-weight reads ----
__global__ void __launch_bounds__(256)
k_proj(const float* __restrict__ x, const float* __restrict__ wtc,
       const float* __restrict__ b1, const float* __restrict__ b2,
       float* __restrict__ sm, float* __restrict__ sv)
{
    int blk = blockIdx.x;          // b*256 + lt
    int b = blk >> 8, l0 = (blk & 255) * 4;
    int tid = threadIdx.x;
    __shared__ float4 xs[256];
    xs[tid] = *(const float4*)(x + ((size_t)(b*256 + tid))*1024 + l0);
    __syncthreads();
    int o = tid & 127;
    float bias = (tid < 128) ? b1[o] : b2[o];
    float a0 = bias, a1 = bias, a2 = bias, a3 = bias;
    #pragma unroll 4
    for (int c = 0; c < 256; ++c){
        float wv = wtc[(size_t)c*256 + tid];
        float4 xv = xs[c];
        a0 = fmaf(wv, xv.x, a0);
        a1 = fmaf(wv, xv.y, a1);
        a2 = fmaf(wv, xv.z, a2);
        a3 = fmaf(wv, xv.w, a3);
    }
    float* dst = (tid < 128) ? sm : sv;
    size_t base = ((size_t)b*1024 + l0)*128 + o;
    dst[base      ] = a0;
    dst[base + 128] = a1;
    dst[base + 256] = a2;
    dst[base + 384] = a3;
}

// ================= LN(128) + matmul (128->512), 8 rows per block =================
__device__ __forceinline__ void lnmm_core(int bl0, float4 v,
    const float* __restrict__ lnw, const float* __restrict__ lnb,
    const float* __restrict__ inw, float* __restrict__ u, float* __restrict__ z,
    float (*hn)[132])
{
    int tid = threadIdx.x;
    int row = tid >> 5, lane = tid & 31;
    float a = v.x + v.y + v.z + v.w;
    float q = v.x*v.x + v.y*v.y + v.z*v.z + v.w*v.w;
    #pragma unroll
    for (int o = 16; o; o >>= 1){ a += __shfl_xor(a, o); q += __shfl_xor(q, o); }
    float mean = a * (1.0f/128.0f);
    float rs = rsqrtf(q * (1.0f/128.0f) - mean*mean + 1e-5f);
    float4 w4 = *(const float4*)(lnw + lane*4);
    float4 b4 = *(const float4*)(lnb + lane*4);
    float4 hv;
    hv.x = (v.x-mean)*rs*w4.x + b4.x;
    hv.y = (v.y-mean)*rs*w4.y + b4.y;
    hv.z = (v.z-mean)*rs*w4.z + b4.z;
    hv.w = (v.w-mean)*rs*w4.w + b4.w;
    *(float4*)&hn[row][lane*4] = hv;
    __syncthreads();
    float acc0[8] = {0,0,0,0,0,0,0,0};
    float acc1[8] = {0,0,0,0,0,0,0,0};
    for (int c = 0; c < 128; c += 4){
        float w0[4], w1[4];
        #pragma unroll
        for (int i = 0; i < 4; ++i){
            w0[i] = inw[(size_t)(c+i)*512 + tid];
            w1[i] = inw[(size_t)(c+i)*512 + tid + 256];
        }
        #pragma unroll
        for (int r = 0; r < 8; ++r){
            float4 h4 = *(const float4*)&hn[r][c];
            acc0[r] = fmaf(h4.x, w0[0], acc0[r]);
            acc0[r] = fmaf(h4.y, w0[1], acc0[r]);
            acc0[r] = fmaf(h4.z, w0[2], acc0[r]);
            acc0[r] = fmaf(h4.w, w0[3], acc0[r]);
            acc1[r] = fmaf(h4.x, w1[0], acc1[r]);
            acc1[r] = fmaf(h4.y, w1[1], acc1[r]);
            acc1[r] = fmaf(h4.z, w1[2], acc1[r]);
            acc1[r] = fmaf(h4.w, w1[3], acc1[r]);
        }
    }
    #pragma unroll
    for (int r = 0; r < 8; ++r){
        u[(size_t)(bl0 + r)*256 + tid] = acc0[r];
        z[(size_t)(bl0 + r)*256 + tid] = acc1[r];
    }
}

__global__ void __launch_bounds__(256)
k_lnmm2(const float* __restrict__ sm_, const float* __restrict__ mlnw, const float* __restrict__ mlnb,
        const float* __restrict__ minw, float* __restrict__ um, float* __restrict__ zm,
        const float* __restrict__ sv_, const float* __restrict__ vlnw, const float* __restrict__ vlnb,
        const float* __restrict__ vinw, float* __restrict__ uv, float* __restrict__ zv)
{
    __shared__ float hn[8][132];
    int tid = threadIdx.x;
    int row = tid >> 5, lane = tid & 31;
    if (blockIdx.x < 256){
        int bl0 = blockIdx.x*8;
        float4 v = *(const float4*)(sm_ + (size_t)(bl0 + row)*128 + lane*4);
        lnmm_core(bl0, v, mlnw, mlnb, minw, um, zm, hn);
    } else {
        int bl0 = (blockIdx.x-256)*8;
        float4 v = *(const float4*)(sv_ + (size_t)(bl0 + row)*128 + lane*4);
        lnmm_core(bl0, v, vlnw, vlnb, vinw, uv, zv, hn);
    }
}

// ================= conv: mamba causal K=4 (blocks 0-2047) + vss dw3x3+scatter =================
__global__ void __launch_bounds__(256)
k_conv2(const float* __restrict__ urm, const float* __restrict__ cwm, const float* __restrict__ cbm,
        float* __restrict__ uc,
        const float* __restrict__ urv, const float* __restrict__ cwv, const float* __restrict__ cbv,
        float* __restrict__ us)
{
    int d = threadIdx.x;
    if (blockIdx.x < 2048){
        int bl = blockIdx.x; int b = bl >> 10, l = bl & 1023;
        float acc = cbm[d];
        #pragma unroll
        for (int k = 0; k < 4; ++k){
            int lp = l - 3 + k;
            if (lp >= 0) acc = fmaf(urm[((size_t)(b<<10) + lp)*256 + d], cwm[d*4 + k], acc);
        }
        uc[(size_t)bl*256 + d] = dev_silu(acc);
    } else {
        int bl = blockIdx.x - 2048; int b = bl >> 10, l = bl & 1023;
        int h = l >> 5, w = l & 31;
        float acc = cbv[d];
        #pragma unroll
        for (int kh = 0; kh < 3; ++kh){
            int hh = h + kh - 1; if (hh < 0 || hh > 31) continue;
            #pragma unroll
            for (int kw = 0; kw < 3; ++kw){
                int ww = w + kw - 1; if (ww < 0 || ww > 31) continue;
                acc = fmaf(urv[((size_t)(b<<10) + (hh<<5) + ww)*256 + d], cwv[d*9 + kh*3 + kw], acc);
            }
        }
        float v = dev_silu(acc);
        int l1 = (w<<5) + h;
        size_t base = (size_t)b*4*1024*256;
        us[base + ((size_t)0*1024 + l        )*256 + d] = v;
        us[base + ((size_t)1*1024 + l1       )*256 + d] = v;
        us[base + ((size_t)2*1024 + (1023-l ))*256 + d] = v;
        us[base + ((size_t)3*1024 + (1023-l1))*256 + d] = v;
    }
}

// ================= xproj: 4 l-positions per block (R7-verified) =================
__device__ __forceinline__ void xproj_body(size_t idx0, int k, const float* __restrict__ u,
    const float* __restrict__ xw, const float* __restrict__ dtw, const float* __restrict__ dtb,
    float* __restrict__ dt, float* __restrict__ Bm, float* __restrict__ Cm)
{
    int tid = threadIdx.x;
    __shared__ float ursh[4][256];
    __shared__ float dbc[4][44];
    #pragma unroll
    for (int p = 0; p < 4; ++p)
        ursh[p][tid] = u[(idx0 + p)*256 + tid];
    __syncthreads();
    if (tid < 160){
        int r = tid % 40, p = tid / 40;
        const float* xwc = xw + (size_t)k*256*40 + r;
        float a0 = 0.f, a1 = 0.f;
        for (int c = 0; c < 128; ++c){
            a0 = fmaf(ursh[p][c],       xwc[(size_t)c*40],       a0);
            a1 = fmaf(ursh[p][c + 128], xwc[(size_t)(c+128)*40], a1);
        }
        dbc[p][r] = a0 + a1;
    }
    __syncthreads();
    const float* dtwk = dtw + (size_t)k*8*256;
    float bias = dtb[k*256 + tid];
    float wv[8];
    #pragma unroll
    for (int r = 0; r < 8; ++r) wv[r] = dtwk[r*256 + tid];
    #pragma unroll
    for (int p = 0; p < 4; ++p){
        float a = bias;
        #pragma unroll
        for (int r = 0; r < 8; ++r) a = fmaf(dbc[p][r], wv[r], a);
        dt[(idx0 + p)*256 + tid] = dev_softplus(a);
    }
    if (tid < 128){
        int p = tid >> 5, j = tid & 31;
        if (j < 16) Bm[(idx0 + p)*16 + j]        = dbc[p][8 + j];
        else        Cm[(idx0 + p)*16 + (j - 16)] = dbc[p][8 + j];
    }
}

__global__ void __launch_bounds__(256)
k_xproj2(const float* __restrict__ um, const float* __restrict__ mxw, const float* __restrict__ mdtw,
         const float* __restrict__ mdtb, float* __restrict__ dtm, float* __restrict__ Bmm,
         float* __restrict__ Cmm,
         const float* __restrict__ uv, const float* __restrict__ vxw, const float* __restrict__ vdtw,
         const float* __restrict__ vdtb, float* __restrict__ dtv, float* __restrict__ Bmv,
         float* __restrict__ Cmv)
{
    if (blockIdx.x < 512){
        int bk = blockIdx.x >> 8;
        size_t idx0 = (size_t)bk*1024 + (blockIdx.x & 255)*4;
        xproj_body(idx0, 0, um, mxw, mdtw, mdtb, dtm, Bmm, Cmm);
    } else {
        int blk = blockIdx.x - 512;
        int bk = blk >> 8;
        size_t idx0 = (size_t)bk*1024 + (blk & 255)*4;
        xproj_body(idx0, bk & 3, uv, vxw, vdtw, vdtb, dtv, Bmv, Cmv);
    }
}

// ================= scan pass A (R7-verified) =================
__device__ __forceinline__ void scanA_body(int bk, int c, int k, const float* __restrict__ dt,
    const float* __restrict__ u, const float* __restrict__ Bm, const float* __restrict__ Alog,
    float* __restrict__ Pb, float* __restrict__ Qb)
{
    int d = threadIdx.x;
    __shared__ float Bsh[CH][16];
    {
        int j = threadIdx.x >> 4, s = threadIdx.x & 15;
        Bsh[j][s] = Bm[((size_t)bk*1024 + c*CH + j)*16 + s];
    }
    float dtv[CH], duv[CH];
    size_t base = ((size_t)bk*1024 + c*CH)*256 + d;
    #pragma unroll
    for (int j = 0; j < CH; ++j){
        float a = dt[base + (size_t)j*256];
        float b = u [base + (size_t)j*256];
        dtv[j] = a; duv[j] = a*b;
    }
    float A[16];
    const float4* Ap = (const float4*)(Alog + ((size_t)k*256 + d)*16);
    #pragma unroll
    for (int q = 0; q < 4; ++q){
        float4 v = Ap[q];
        A[q*4+0] = -__expf(v.x); A[q*4+1] = -__expf(v.y);
        A[q*4+2] = -__expf(v.z); A[q*4+3] = -__expf(v.w);
    }
    __syncthreads();
    float Q[16];
    #pragma unroll
    for (int s = 0; s < 16; ++s) Q[s] = 0.f;
    float S = 0.f;
    #pragma unroll
    for (int j = 0; j < CH; ++j){
        S += dtv[j];
        #pragma unroll
        for (int s = 0; s < 16; ++s){
            float av = __expf(dtv[j]*A[s]);
            Q[s] = fmaf(av, Q[s], duv[j]*Bsh[j][s]);
        }
    }
    size_t oidx = ((size_t)(bk*NCH + c)*256 + d)*16;
    float4* Pp = (float4*)(Pb + oidx);
    float4* Qp = (float4*)(Qb + oidx);
    #pragma unroll
    for (int q = 0; q < 4; ++q){
        float4 pv, qv;
        pv.x = __expf(S*A[q*4+0]); pv.y = __expf(S*A[q*4+1]);
        pv.z = __expf(S*A[q*4+2]); pv.w = __expf(S*A[q*4+3]);
        qv.x = Q[q*4+0]; qv.y = Q[q*4+1]; qv.z = Q[q*4+2]; qv.w = Q[q*4+3];
        Pp[q] = pv; Qp[q] = qv;
    }
}

__global__ void __launch_bounds__(256)
k_scanA2(const float* __restrict__ dtm, const float* __restrict__ um, const float* __restrict__ Bmm,
         const float* __restrict__ mAlog, float* __restrict__ Pbm, float* __restrict__ Qbm,
         const float* __restrict__ dtv, const float* __restrict__ uv, const float* __restrict__ Bmv,
         const float* __restrict__ vAlog, float* __restrict__ Pbv, float* __restrict__ Qbv)
{
    if (blockIdx.x < 128){
        int blk = blockIdx.x;
        scanA_body(blk >> 6, blk & (NCH-1), 0, dtm, um, Bmm, mAlog, Pbm, Qbm);
    } else {
        int blk = blockIdx.x - 128;
        int bk = blk >> 6;
        scanA_body(bk, blk & (NCH-1), bk & 3, dtv, uv, Bmv, vAlog, Pbv, Qbv);
    }
}

// ================= scan pass P =================
__device__ __forceinline__ void scanP_body(int bk, int dg, float* __restrict__ Pb,
                                           const float* __restrict__ Qb)
{
    int tid = threadIdx.x;
    size_t idx0 = (size_t)bk*NCH*4096 + dg*256 + tid;
    float Pv[NCH], Qv[NCH];
    #pragma unroll
    for (int c = 0; c < NCH; ++c){
        Pv[c] = Pb[idx0 + (size_t)c*4096];
        Qv[c] = Qb[idx0 + (size_t)c*4096];
    }
    float h = 0.f;
    #pragma unroll
    for (int c = 0; c < NCH; ++c){
        Pb[idx0 + (size_t)c*4096] = h;
        h = fmaf(Pv[c], h, Qv[c]);
    }
}

__global__ void __launch_bounds__(256)
k_scanP2(float* __restrict__ Pbm, const float* __restrict__ Qbm,
         float* __restrict__ Pbv, const float* __restrict__ Qbv)
{
    if (blockIdx.x < 32) scanP_body(blockIdx.x >> 4, blockIdx.x & 15, Pbm, Qbm);
    else { int blk = blockIdx.x - 32; scanP_body(blk >> 4, blk & 15, Pbv, Qbv); }
}

// ================= scan pass B =================
__device__ __forceinline__ void scanB_body(int bk, int c, int k, const float* __restrict__ dt,
    const float* __restrict__ u, const float* __restrict__ Bm, const float* __restrict__ Cm,
    const float* __restrict__ Alog, const float* __restrict__ Hb, float* __restrict__ y)
{
    int d = threadIdx.x;
    __shared__ float Bsh[CH][16], Csh[CH][16];
    {
        int j = threadIdx.x >> 4, s = threadIdx.x & 15;
        size_t bi = ((size_t)bk*1024 + c*CH + j)*16 + s;
        Bsh[j][s] = Bm[bi];
        Csh[j][s] = Cm[bi];
    }
    float dtv[CH], duv[CH];
    size_t base = ((size_t)bk*1024 + c*CH)*256 + d;
    #pragma unroll
    for (int j = 0; j < CH; ++j){
        float a = dt[base + (size_t)j*256];
        float b = u [base + (size_t)j*256];
        dtv[j] = a; duv[j] = a*b;
    }
    float A[16];
    const float4* Ap = (const float4*)(Alog + ((size_t)k*256 + d)*16);
    #pragma unroll
    for (int q = 0; q < 4; ++q){
        float4 v = Ap[q];
        A[q*4+0] = -__expf(v.x); A[q*4+1] = -__expf(v.y);
        A[q*4+2] = -__expf(v.z); A[q*4+3] = -__expf(v.w);
    }
    float h[16];
    const float4* Hp = (const float4*)(Hb + ((size_t)(bk*NCH + c)*256 + d)*16);
    #pragma unroll
    for (int q = 0; q < 4; ++q){
        float4 v = Hp[q];
        h[q*4+0] = v.x; h[q*4+1] = v.y; h[q*4+2] = v.z; h[q*4+3] = v.w;
    }
    __syncthreads();
    float* yp = y + base;
    #pragma unroll
    for (int j = 0; j < CH; ++j){
        float py = 0.f;
        #pragma unroll
        for (int s = 0; s < 16; ++s){
            float av = __expf(dtv[j]*A[s]);
            h[s] = fmaf(av, h[s], duv[j]*Bsh[j][s]);
            py = fmaf(h[s], Csh[j][s], py);
        }
        yp[(size_t)j*256] = py;
    }
}

__global__ void __launch_bounds__(256)
k_scanB2(const float* __restrict__ dtm, const float* __restrict__ um, const float* __restrict__ Bmm,
         const float* __restrict__ Cmm, const float* __restrict__ mAlog,
         const float* __restrict__ Hbm, float* __restrict__ ym,
         const float* __restrict__ dtv, const float* __restrict__ uv, const float* __restrict__ Bmv,
         const float* __restrict__ Cmv, const float* __restrict__ vAlog,
         const float* __restrict__ Hbv, float* __restrict__ yv)
{
    if (blockIdx.x < 128){
        int blk = blockIdx.x;
        scanB_body(blk >> 6, blk & (NCH-1), 0, dtm, um, Bmm, Cmm, mAlog, Hbm, ym);
    } else {
        int blk = blockIdx.x - 128;
        int bk = blk >> 6;
        scanB_body(bk, blk & (NCH-1), bk & 3, dtv, uv, Bmv, Cmv, vAlog, Hbv, yv);
    }
}

// ================= epilogues =================
__device__ __forceinline__ void mout_body(int bl0, const float* __restrict__ y,
    const float* __restrict__ uc, const float* __restrict__ z, const float* __restrict__ Dp,
    const float* __restrict__ ow, float* __restrict__ sm)
{
    int tid = threadIdx.x;
    int row = tid >> 5, c0 = (tid & 31) * 8;
    __shared__ float gld[8][264];
    size_t base = (size_t)(bl0 + row)*256 + c0;
    #pragma unroll
    for (int i = 0; i < 8; i += 4){
        float4 yv = *(const float4*)(y + base + i);
        float4 uv = *(const float4*)(uc + base + i);
        float4 zv = *(const float4*)(z + base + i);
        float4 dv = *(const float4*)(Dp + c0 + i);
        gld[row][c0+i+0] = (yv.x + uv.x*dv.x) * dev_silu(zv.x);
        gld[row][c0+i+1] = (yv.y + uv.y*dv.y) * dev_silu(zv.y);
        gld[row][c0+i+2] = (yv.z + uv.z*dv.z) * dev_silu(zv.z);
        gld[row][c0+i+3] = (yv.w + uv.w*dv.w) * dev_silu(zv.w);
    }
    __syncthreads();
    int o = tid & 127, rg = tid >> 7;
    float acc[4] = {0,0,0,0};
    for (int c = 0; c < 256; c += 4){
        float w[4];
        #pragma unroll
        for (int i = 0; i < 4; ++i) w[i] = ow[(size_t)(c+i)*128 + o];
        #pragma unroll
        for (int r = 0; r < 4; ++r){
            float4 h4 = *(const float4*)&gld[rg*4 + r][c];
            acc[r] = fmaf(h4.x, w[0], acc[r]);
            acc[r] = fmaf(h4.y, w[1], acc[r]);
            acc[r] = fmaf(h4.z, w[2], acc[r]);
            acc[r] = fmaf(h4.w, w[3], acc[r]);
        }
    }
    #pragma unroll
    for (int r = 0; r < 4; ++r)
        sm[(size_t)(bl0 + rg*4 + r)*128 + o] += acc[r];
}

__device__ __forceinline__ void vcomb_body(int blk, const float* __restrict__ y,
    const float* __restrict__ us, const float* __restrict__ z, const float* __restrict__ Dp,
    const float* __restrict__ onw, const float* __restrict__ onb, const float* __restrict__ ow,
    float* __restrict__ sv)
{
    int b = blk >> 7;
    int l0 = (blk & 127) * 8;
    int tid = threadIdx.x;
    int row = tid >> 5, c0 = (tid & 31) * 8;
    int l = l0 + row;
    int h = l >> 5, w = l & 31;
    int l1 = (w<<5) + h, l2 = 1023 - l, l3 = 1023 - l1;
    size_t base = (size_t)b*4*1024*256;
    size_t i0 = base + ((size_t)0*1024 + l )*256 + c0;
    size_t i1 = base + ((size_t)1*1024 + l1)*256 + c0;
    size_t i2 = base + ((size_t)2*1024 + l2)*256 + c0;
    size_t i3 = base + ((size_t)3*1024 + l3)*256 + c0;
    float t[8];
    #pragma unroll
    for (int i = 0; i < 8; i += 4){
        float4 yv = *(const float4*)(y + i0 + i);
        float4 uv = *(const float4*)(us + i0 + i);
        float4 dv = *(const float4*)(Dp + 0*256 + c0 + i);
        t[i+0] = yv.x + uv.x*dv.x; t[i+1] = yv.y + uv.y*dv.y;
        t[i+2] = yv.z + uv.z*dv.z; t[i+3] = yv.w + uv.w*dv.w;
    }
    #pragma unroll
    for (int i = 0; i < 8; i += 4){
        float4 yv = *(const float4*)(y + i1 + i);
        float4 uv = *(const float4*)(us + i1 + i);
        float4 dv = *(const float4*)(Dp + 1*256 + c0 + i);
        t[i+0] += yv.x + uv.x*dv.x; t[i+1] += yv.y + uv.y*dv.y;
        t[i+2] += yv.z + uv.z*dv.z; t[i+3] += yv.w + uv.w*dv.w;
    }
    #pragma unroll
    for (int i = 0; i < 8; i += 4){
        float4 yv = *(const float4*)(y + i2 + i);
        float4 uv = *(const float4*)(us + i2 + i);
        float4 dv = *(const float4*)(Dp + 2*256 + c0 + i);
        t[i+0] += yv.x + uv.x*dv.x; t[i+1] += yv.y + uv.y*dv.y;
        t[i+2] += yv.z + uv.z*dv.z; t[i+3] += yv.w + uv.w*dv.w;
    }
    #pragma unroll
    for (int i = 0; i < 8; i += 4){
        float4 yv = *(const float4*)(y + i3 + i);
        float4 uv = *(const float4*)(us + i3 + i);
        float4 dv = *(const float4*)(Dp + 3*256 + c0 + i);
        t[i+0] += yv.x + uv.x*dv.x; t[i+1] += yv.y + uv.y*dv.y;
        t[i+2] += yv.z + uv.z*dv.z; t[i+3] += yv.w + uv.w*dv.w;
    }
    float a = 0.f, q = 0.f;
    #pragma unroll
    for (int i = 0; i < 8; ++i){ a += t[i]; q += t[i]*t[i]; }
    #pragma unroll
    for (int o = 16; o; o >>= 1){ a += __shfl_xor(a, o); q += __shfl_xor(q, o); }
    float mean = a * (1.0f/256.0f);
    float rs = rsqrtf(q * (1.0f/256.0f) - mean*mean + 1e-5f);
    __shared__ float gld[8][264];
    size_t zbase = (size_t)(b*1024 + l)*256 + c0;
    #pragma unroll
    for (int i = 0; i < 8; i += 4){
        float4 wv = *(const float4*)(onw + c0 + i);
        float4 bv = *(const float4*)(onb + c0 + i);
        float4 zv = *(const float4*)(z + zbase + i);
        gld[row][c0+i+0] = ((t[i+0]-mean)*rs*wv.x + bv.x) * dev_silu(zv.x);
        gld[row][c0+i+1] = ((t[i+1]-mean)*rs*wv.y + bv.y) * dev_silu(zv.y);
        gld[row][c0+i+2] = ((t[i+2]-mean)*rs*wv.z + bv.z) * dev_silu(zv.z);
        gld[row][c0+i+3] = ((t[i+3]-mean)*rs*wv.w + bv.w) * dev_silu(zv.w);
    }
    __syncthreads();
    int o = tid & 127, rg = tid >> 7;
    float acc[4] = {0,0,0,0};
    for (int c = 0; c < 256; c += 4){
        float wv[4];
        #pragma unroll
        for (int i = 0; i < 4; ++i) wv[i] = ow[(size_t)(c+i)*128 + o];
        #pragma unroll
        for (int r = 0; r < 4; ++r){
            float4 h4 = *(const float4*)&gld[rg*4 + r][c];
            acc[r] = fmaf(h4.x, wv[0], acc[r]);
            acc[r] = fmaf(h4.y, wv[1], acc[r]);
            acc[r] = fmaf(h4.z, wv[2], acc[r]);
            acc[r] = fmaf(h4.w, wv[3], acc[r]);
        }
    }
    #pragma unroll
    for (int r = 0; r < 4; ++r)
        sv[(size_t)(b*1024 + l0 + rg*4 + r)*128 + o] += acc[r];
}

__global__ void __launch_bounds__(256)
k_epi2(const float* __restrict__ ym, const float* __restrict__ uc, const float* __restrict__ zm,
       const float* __restrict__ mD, const float* __restrict__ mow, float* __restrict__ sm,
       const float* __restrict__ yv, const float* __restrict__ us, const float* __restrict__ zv,
       const float* __restrict__ vD, const float* __restrict__ onw, const float* __restrict__ onb,
       const float* __restrict__ vow, float* __restrict__ sv)
{
    if (blockIdx.x < 256) mout_body(blockIdx.x*8, ym, uc, zm, mD, mow, sm);
    else                  vcomb_body(blockIdx.x-256, yv, us, zv, vD, onw, onb, vow, sv);
}

// ---- im2col (K reordered: kp major, c minor; coalesced): Bt[n][kp*256+c] ----
__global__ void __launch_bounds__(256)
k_im2col(const float* __restrict__ sm, const float* __restrict__ sv,
         unsigned short* __restrict__ Bt)
{
    int n = blockIdx.x; int b = n >> 10, p = n & 1023;
    int h = p >> 5, w = p & 31;
    int tid = threadIdx.x;
    const float* src = (tid < 128) ? sm : sv;
    int c = tid & 127;
    #pragma unroll
    for (int kp = 0; kp < 9; ++kp){
        int kh = kp / 3, kw = kp - kh*3;
        int hh = h + kh - 1, ww = w + kw - 1;
        float v = 0.f;
        if ((unsigned)hh < 32u && (unsigned)ww < 32u)
            v = src[((size_t)b*1024 + (hh<<5) + ww)*128 + c];
        Bt[(size_t)n*2304 + kp*256 + tid] = dev_bf16(v);
    }
}

// ---- bf16 MFMA GEMM (R7-verified loop): out[o][n] = Wr[o][:]·Bt[n][:], + bias + BN + ReLU ----
__global__ void __launch_bounds__(256)
k_fgemm(const unsigned short* __restrict__ Wr, const unsigned short* __restrict__ Bt,
        const float* __restrict__ fb, const float* __restrict__ bg, const float* __restrict__ bb,
        const float* __restrict__ bm, const float* __restrict__ bv, float* __restrict__ out)
{
    int o0 = (blockIdx.x & 3) * 64;
    int n0 = (blockIdx.x >> 2) * 64;
    int tid = threadIdx.x, lane = tid & 63, wid = tid >> 6;
    int wm = (wid >> 1) * 32, wn = (wid & 1) * 32;
    __shared__ unsigned short sA[64*40];   // rows padded to 80B (bank-even)
    __shared__ unsigned short sB[64*40];
    f32x4 acc[2][2] = {};
    int srow = tid >> 2, scol = (tid & 3) * 8;
    const u32x4* gA = (const u32x4*)(Wr + (size_t)(o0 + srow)*2304 + scol);
    const u32x4* gB = (const u32x4*)(Bt + (size_t)(n0 + srow)*2304 + scol);
    u32x4* wA = (u32x4*)(sA + srow*40 + scol);
    u32x4* wB = (u32x4*)(sB + srow*40 + scol);
    int fr = lane & 15, fk = (lane >> 4) * 8;
    const unsigned short* rA0 = sA + (wm + fr)*40 + fk;
    const unsigned short* rA1 = sA + (wm + 16 + fr)*40 + fk;
    const unsigned short* rB0 = sB + (wn + fr)*40 + fk;
    const unsigned short* rB1 = sB + (wn + 16 + fr)*40 + fk;
    for (int kt = 0; kt < 72; ++kt){
        u32x4 va = gA[kt*4];
        u32x4 vb = gB[kt*4];
        __syncthreads();
        *wA = va; *wB = vb;
        __syncthreads();
        bf16x8 a0 = *(const bf16x8*)rA0;
        bf16x8 a1 = *(const bf16x8*)rA1;
        bf16x8 b0 = *(const bf16x8*)rB0;
        bf16x8 b1 = *(const bf16x8*)rB1;
        acc[0][0] = __builtin_amdgcn_mfma_f32_16x16x32_bf16(a0, b0, acc[0][0], 0, 0, 0);
        acc[0][1] = __builtin_amdgcn_mfma_f32_16x16x32_bf16(a0, b1, acc[0][1], 0, 0, 0);
        acc[1][0] = __builtin_amdgcn_mfma_f32_16x16x32_bf16(a1, b0, acc[1][0], 0, 0, 0);
        acc[1][1] = __builtin_amdgcn_mfma_f32_16x16x32_bf16(a1, b1, acc[1][1], 0, 0, 0);
    }
    #pragma unroll
    for (int i = 0; i < 2; ++i){
        int ob = o0 + wm + i*16 + (lane >> 4) * 4;
        #pragma unroll
        for (int j = 0; j < 2; ++j){
            int n = n0 + wn + j*16 + (lane & 15);
            int b = n >> 10, p = n & 1023;
            #pragma unroll
            for (int q = 0; q < 4; ++q){
                int o = ob + q;
                float v = acc[i][j][q] + fb[o];
                v = (v - bm[o]) * rsqrtf(bv[o] + 1e-5f) * bg[o] + bb[o];
                out[((size_t)(b*256 + o))*1024 + p] = fmaxf(v, 0.f);
            }
        }
    }
}

extern "C" void kernel_launch(void* const* d_in, const int* in_sizes, int n_in,
                              void* d_out, int out_size, void* d_ws, size_t ws_size,
                              hipStream_t stream)
{
    const float* x         = (const float*)d_in[0];
    const float* proj1_w   = (const float*)d_in[1];
    const float* proj1_b   = (const float*)d_in[2];
    const float* proj2_w   = (const float*)d_in[3];
    const float* proj2_b   = (const float*)d_in[4];
    const float* m_ln_w    = (const float*)d_in[5];
    const float* m_ln_b    = (const float*)d_in[6];
    const float* m_in_w    = (const float*)d_in[7];
    const float* m_conv_w  = (const float*)d_in[8];
    const float* m_conv_b  = (const float*)d_in[9];
    const float* m_xproj_w = (const float*)d_in[10];
    const float* m_dt_w    = (const float*)d_in[11];
    const float* m_dt_b    = (const float*)d_in[12];
    const float* m_Alog    = (const float*)d_in[13];
    const float* m_D       = (const float*)d_in[14];
    const float* m_out_w   = (const float*)d_in[15];
    const float* v_ln_w    = (const float*)d_in[16];
    const float* v_ln_b    = (const float*)d_in[17];
    const float* v_in_w    = (const float*)d_in[18];
    const float* v_conv_w  = (const float*)d_in[19];
    const float* v_conv_b  = (const float*)d_in[20];
    const float* v_xproj_w = (const float*)d_in[21];
    const float* v_dt_w    = (const float*)d_in[22];
    const float* v_dt_b    = (const float*)d_in[23];
    const float* v_Alog    = (const float*)d_in[24];
    const float* v_D       = (const float*)d_in[25];
    const float* v_onorm_w = (const float*)d_in[26];
    const float* v_onorm_b = (const float*)d_in[27];
    const float* v_out_w   = (const float*)d_in[28];
    const float* fuse_w    = (const float*)d_in[29];
    const float* fuse_b    = (const float*)d_in[30];
    const float* bn_g      = (const float*)d_in[31];
    const float* bn_b      = (const float*)d_in[32];
    const float* bn_m      = (const float*)d_in[33];
    const float* bn_v      = (const float*)d_in[34];
    float* out = (float*)d_out;

    float* ws = (float*)d_ws;
    float* sm     = ws;  ws += 2*1024*128;
    float* sv     = ws;  ws += 2*1024*128;
    float* uraw_m = ws;  ws += 2*1024*256;
    float* zb_m   = ws;  ws += 2*1024*256;
    float* uc     = ws;  ws += 2*1024*256;     // mamba post-conv u
    float* uraw_v = ws;  ws += 2*1024*256;
    float* zb_v   = ws;  ws += 2*1024*256;
    float* usb    = ws;  ws += 2*4*1024*256;   // vss 4-direction sequences
    float* dt_m   = ws;  ws += 2*1024*256;
    float* yb_m   = ws;  ws += 2*1024*256;
    float* Pb_m   = ws;  ws += 2*NCH*256*16;
    float* Qb_m   = ws;  ws += 2*NCH*256*16;
    float* Bm_m   = ws;  ws += 2*1024*16;
    float* Cm_m   = ws;  ws += 2*1024*16;
    float* dt_v   = ws;  ws += 2*4*1024*256;   // (followed by yb_v for Bmat alias)
    float* yb_v   = ws;  ws += 2*4*1024*256;
    float* Pb_v   = ws;  ws += 2*4*NCH*256*16;
    float* Qb_v   = ws;  ws += 2*4*NCH*256*16;
    float* Bm_v   = ws;  ws += 2*4*1024*16;
    float* Cm_v   = ws;  ws += 2*4*1024*16;
    float* wtc    = ws;  ws += 256*256;
    unsigned short* Wr = (unsigned short*)ws;  ws += 576*1024/2;
    unsigned short* Bmat = (unsigned short*)dt_v;   // 9.44 MB <= dt_v+yb_v (16.8 MB), dead by then

    k_prep<<<640,   256, 0, stream>>>(proj1_w, proj2_w, wtc, fuse_w, Wr);
    k_proj<<<2*256, 256, 0, stream>>>(x, wtc, proj1_b, proj2_b, sm, sv);

    for (int i = 0; i < 2; ++i){
        k_lnmm2 <<<512,  256, 0, stream>>>(sm, m_ln_w + i*128, m_ln_b + i*128,
                                           m_in_w + (size_t)i*65536, uraw_m, zb_m,
                                           sv, v_ln_w + i*128, v_ln_b + i*128,
                                           v_in_w + (size_t)i*65536, uraw_v, zb_v);
        k_conv2 <<<4096, 256, 0, stream>>>(uraw_m, m_conv_w + (size_t)i*1024, m_conv_b + i*256, uc,
                                           uraw_v, v_conv_w + (size_t)i*2304, v_conv_b + i*256, usb);
        k_xproj2<<<2560, 256, 0, stream>>>(uc,  m_xproj_w + (size_t)i*10240,
                                           m_dt_w + (size_t)i*2048, m_dt_b + i*256,
                                           dt_m, Bm_m, Cm_m,
                                           usb, v_xproj_w + (size_t)i*40960,
                                           v_dt_w + (size_t)i*8192, v_dt_b + (size_t)i*1024,
                                           dt_v, Bm_v, Cm_v);
        k_scanA2<<<640,  256, 0, stream>>>(dt_m, uc,  Bm_m, m_Alog + (size_t)i*4096,  Pb_m, Qb_m,
                                           dt_v, usb, Bm_v, v_Alog + (size_t)i*16384, Pb_v, Qb_v);
        k_scanP2<<<160,  256, 0, stream>>>(Pb_m, Qb_m, Pb_v, Qb_v);
        k_scanB2<<<640,  256, 0, stream>>>(dt_m, uc,  Bm_m, Cm_m, m_Alog + (size_t)i*4096,
                                           Pb_m, yb_m,
                                           dt_v, usb, Bm_v, Cm_v, v_Alog + (size_t)i*16384,
                                           Pb_v, yb_v);
        k_epi2  <<<512,  256, 0, stream>>>(yb_m, uc, zb_m, m_D + i*256,
                                           m_out_w + (size_t)i*32768, sm,
                                           yb_v, usb, zb_v, v_D + (size_t)i*1024,
                                           v_onorm_w + i*256, v_onorm_b + i*256,
                                           v_out_w + (size_t)i*32768, sv);
    }

    k_im2col<<<2*1024, 256, 0, stream>>>(sm, sv, Bmat);
    k_fgemm <<<4*32,   256, 0, stream>>>(Wr, Bmat, fuse_b, bn_g, bn_b, bn_m, bn_v, out);
}